// Round 16
// baseline (7742.246 us; speedup 1.0000x reference)
//
#include <hip/hip_runtime.h>
#include <cstdint>
#include <cstddef>

// ---------------- problem dims ----------------
#define SS   256
#define BB   32
#define EE   768
#define HH   1024
#define QQ   64
#define TTOP 512
#define NPC  16
#define G4   4096          // 4*H
#define TCHUNK 32
#define NBLK 256
#define EPSF 1e-5f

// ---------------- ws layout (floats) ----------------
#define OFF_XNT   ((size_t)0)                       // [256][768][32]   (6,291,456)
#define OFF_WHHT  ((size_t)6291456)                 // [2][1024][4096]  (8,388,608)
#define OFF_CT    ((size_t)14680064)                // [2][1024][32]    (65,536)
#define OFF_HBUF  ((size_t)14745600)                // [2][2][1024][32] (131,072)
#define OFF_CNT   ((size_t)14876672)                // barrier lines    (512)
#define OFF_XG    ((size_t)14877184)                // [32][8192][32]   (8,388,608)
#define OFF_HS    ((size_t)23265792)                // [2][256][1024][32] (16,777,216)  [j][b]
#define OFF_XQ    ((size_t)40043008)                // [2][256][32][64] (1,048,576)
// post-LSTM overlays inside XNT region (xnT dead after last k_xg):
#define OFF_CMAT  ((size_t)0)                       // [64][256][64]  (1,048,576)
#define OFF_COV   ((size_t)1048576)                 // [64][64][64]   (262,144)
#define OFF_PG    ((size_t)1310720)                 // [64][64][16]   (65,536)
#define OFF_COS   ((size_t)1376256)                 // [64][256]      (16,384)

// k_lstm dynamic LDS: Wl[8][128][32]=131072B + red[4][16][64]=16384B
//                   + gl[32][36]=4608B + cls[8][32]=1024B  -> 153088B
#define LSTM_DYN_LDS 153088

// k_eig: 4 matrices padded to 64x65 f64
#define AST 65
#define EIG_DYN_LDS 133120

// LAPACK f32 machine constants (branch thresholds; math in f64)
#define EPS32D    5.9604644775390625e-8
#define EPS232D   (EPS32D*EPS32D)
#define SAFMIN32D 1.1754943508222875e-38

__device__ __forceinline__ float sigm(float x){ return 1.0f/(1.0f + expf(-x)); }

__device__ __forceinline__ double wsumd(double v){
  #pragma unroll
  for (int o = 32; o; o >>= 1) v += __shfl_xor(v, o, 64);
  return v;
}
__device__ __forceinline__ double wmaxd(double v){
  #pragma unroll
  for (int o = 32; o; o >>= 1) v = fmax(v, __shfl_xor(v, o, 64));
  return v;
}
__device__ __forceinline__ void dlartg_(double f, double g, double& c, double& s, double& r){
  if (g == 0.0){ c = 1.0; s = 0.0; r = f; }
  else if (f == 0.0){ c = 0.0; s = (g >= 0.0) ? 1.0 : -1.0; r = fabs(g); }
  else {
    double d = sqrt(f*f + g*g);
    c = fabs(f)/d;
    r = copysign(d, f);
    s = g/r;
  }
}
__device__ void dlaev2_(double a, double b, double c,
                        double& rt1, double& rt2, double& cs1, double& sn1){
  double sm = a + c, df = a - c, adf = fabs(df), tb = b + b, ab = fabs(tb);
  double acmx, acmn;
  if (fabs(a) > fabs(c)){ acmx = a; acmn = c; } else { acmx = c; acmn = a; }
  double rt;
  if (adf > ab)      rt = adf*sqrt(1.0 + (ab/adf)*(ab/adf));
  else if (adf < ab) rt = ab*sqrt(1.0 + (adf/ab)*(adf/ab));
  else               rt = ab*sqrt(2.0);
  int sgn1;
  if (sm < 0.0){ rt1 = 0.5*(sm - rt); sgn1 = -1; rt2 = (acmx/rt1)*acmn - (b/rt1)*b; }
  else if (sm > 0.0){ rt1 = 0.5*(sm + rt); sgn1 = 1; rt2 = (acmx/rt1)*acmn - (b/rt1)*b; }
  else { rt1 = 0.5*rt; rt2 = -0.5*rt; sgn1 = 1; }
  double cs; int sgn2;
  if (df >= 0.0){ cs = df + rt; sgn2 = 1; } else { cs = df - rt; sgn2 = -1; }
  double acs = fabs(cs);
  if (acs > ab){ double ct = -tb/cs; sn1 = 1.0/sqrt(1.0+ct*ct); cs1 = ct*sn1; }
  else {
    if (ab == 0.0){ cs1 = 1.0; sn1 = 0.0; }
    else { double tn = -cs/tb; cs1 = 1.0/sqrt(1.0+tn*tn); sn1 = tn*cs1; }
  }
  if (sgn1 == sgn2){ double tn = cs1; cs1 = -sn1; sn1 = tn; }
}

// wave-synchronous (NO __syncthreads inside): one leaf per wave.
__device__ void dsteqr16_(int base, double* d, double* e, double* z16, int ln,
                          double* tmpd, double* tmpz, int* rk){
  if (ln < 16){
    #pragma unroll
    for (int j = 0; j < 16; j++) z16[ln*17+j] = (ln==j) ? 1.0 : 0.0;
  }
  const int n = 16, nm1 = 15;
  int jtot = 0; const int nmaxit = 480;
  int l1 = 0;
  while (l1 < n){
    if (l1 > 0) e[base+l1-1] = 0.0;
    int m = nm1;
    for (int mm = l1; mm < nm1; mm++){
      double tst = fabs(e[base+mm]);
      if (tst == 0.0){ m = mm; break; }
      if (tst <= (sqrt(fabs(d[base+mm]))*sqrt(fabs(d[base+mm+1])))*EPS32D){
        e[base+mm] = 0.0; m = mm; break;
      }
    }
    int l = l1, lend = m;
    l1 = m + 1;
    if (lend == l) continue;
    if (fabs(d[base+lend]) < fabs(d[base+l])){ int t = l; l = lend; lend = t; }
    if (lend > l){
      for (;;){
        int mm = lend;
        for (int k2 = l; k2 < lend; k2++){
          double tst = e[base+k2]*e[base+k2];
          if (tst <= (EPS232D*fabs(d[base+k2]))*fabs(d[base+k2+1]) + SAFMIN32D){ mm = k2; break; }
        }
        if (mm < lend) e[base+mm] = 0.0;
        double p = d[base+l];
        if (mm == l){ l++; if (l <= lend) continue; break; }
        if (mm == l+1){
          double rt1, rt2, cc, ss;
          dlaev2_(d[base+l], e[base+l], d[base+l+1], rt1, rt2, cc, ss);
          if (ln < 16){
            double x = z16[ln*17+l], y = z16[ln*17+l+1];
            z16[ln*17+l]   = cc*x + ss*y;
            z16[ln*17+l+1] = cc*y - ss*x;
          }
          d[base+l] = rt1; d[base+l+1] = rt2; e[base+l] = 0.0;
          l += 2; if (l <= lend) continue; break;
        }
        if (jtot == nmaxit) break;
        jtot++;
        double g = (d[base+l+1]-p)/(2.0*e[base+l]);
        double r = sqrt(g*g+1.0);
        g = d[base+mm] - p + e[base+l]/(g + copysign(r, g));
        double s2 = 1.0, c2 = 1.0; p = 0.0;
        for (int i = mm-1; i >= l; i--){
          double f = s2*e[base+i], b = c2*e[base+i];
          dlartg_(g, f, c2, s2, r);
          if (i != mm-1) e[base+i+1] = r;
          g = d[base+i+1] - p;
          r = (d[base+i]-g)*s2 + 2.0*c2*b;
          p = s2*r;
          d[base+i+1] = g + p;
          g = c2*r - b;
          if (ln < 16){
            double x = z16[ln*17+i], y = z16[ln*17+i+1];
            z16[ln*17+i]   = c2*x - s2*y;
            z16[ln*17+i+1] = s2*x + c2*y;
          }
        }
        d[base+l] -= p; e[base+l] = g;
      }
    } else {
      for (;;){
        int mm = lend;
        for (int k2 = l; k2 > lend; k2--){
          double tst = e[base+k2-1]*e[base+k2-1];
          if (tst <= (EPS232D*fabs(d[base+k2]))*fabs(d[base+k2-1]) + SAFMIN32D){ mm = k2; break; }
        }
        if (mm > lend) e[base+mm-1] = 0.0;
        double p = d[base+l];
        if (mm == l){ l--; if (l >= lend) continue; break; }
        if (mm == l-1){
          double rt1, rt2, cc, ss;
          dlaev2_(d[base+l-1], e[base+l-1], d[base+l], rt1, rt2, cc, ss);
          if (ln < 16){
            double x = z16[ln*17+l-1], y = z16[ln*17+l];
            z16[ln*17+l-1] = cc*x + ss*y;
            z16[ln*17+l]   = cc*y - ss*x;
          }
          d[base+l-1] = rt1; d[base+l] = rt2; e[base+l-1] = 0.0;
          l -= 2; if (l >= lend) continue; break;
        }
        if (jtot == nmaxit) break;
        jtot++;
        double g = (d[base+l-1]-p)/(2.0*e[base+l-1]);
        double r = sqrt(g*g+1.0);
        g = d[base+mm] - p + e[base+l-1]/(g + copysign(r, g));
        double s2 = 1.0, c2 = 1.0; p = 0.0;
        for (int i = mm; i <= l-1; i++){
          double f = s2*e[base+i], b = c2*e[base+i];
          dlartg_(g, f, c2, s2, r);
          if (i != mm) e[base+i-1] = r;
          g = d[base+i] - p;
          r = (d[base+i+1]-g)*s2 + 2.0*c2*b;
          p = s2*r;
          d[base+i] = g + p;
          g = c2*r - b;
          if (ln < 16){
            double x = z16[ln*17+i], y = z16[ln*17+i+1];
            z16[ln*17+i]   = c2*x + s2*y;
            z16[ln*17+i+1] = c2*y - s2*x;
          }
        }
        d[base+l] -= p; e[base+l-1] = g;
      }
    }
  }
  // rank-based stable sort (ascending)
  if (ln < 16){
    double di = d[base+ln]; int r = 0;
    for (int j = 0; j < 16; j++){
      double dj = d[base+j];
      if (dj < di || (dj == di && j < ln)) r++;
    }
    rk[ln] = r;
    tmpd[r] = di;
  }
  if (ln < 16){
    for (int j = 0; j < 16; j++) tmpz[ln*16 + rk[j]] = z16[ln*17 + j];
    for (int j = 0; j < 16; j++) z16[ln*17 + j] = tmpz[ln*16 + j];
    d[base+ln] = tmpd[ln];
  }
}

// single-wave dc_merge (wave-synchronous, no barriers).
__device__ void dc_merge1(int base, int n1, int n2, double rho_in, int ln,
    double* s_d, double* Zt, double* Ttp,
    double* md, double* mz, double* dl, double* wz, double* lam, double* zh,
    double* ev, double* su, int* indx, int* sec, int* defl, int* prm){
  const int n = n1 + n2;
  double zv = 0.0;
  if (ln < n){
    if (ln < n1) zv = Zt[(size_t)(base+n1-1)*AST + base + ln];
    else         zv = Zt[(size_t)(base+n1)*AST + base + ln];
    if (rho_in < 0.0 && ln >= n1) zv = -zv;
  }
  zv *= 0.70710678118654752440;
  double mdv = (ln < n) ? s_d[base+ln] : 0.0;
  if (ln < n){ mz[ln] = zv; md[ln] = mdv; }
  double rho = fabs(2.0*rho_in);
  if (ln == 0){
    int i1 = 0, i2 = n1, k = 0;
    while (i1 < n1 && i2 < n){
      if (md[i2] < md[i1]) indx[k++] = i2++; else indx[k++] = i1++;
    }
    while (i1 < n1) indx[k++] = i1++;
    while (i2 < n)  indx[k++] = i2++;
  }
  double dmax = wmaxd((ln<n) ? fabs(mdv) : 0.0);
  double zmax = wmaxd((ln<n) ? fabs(zv) : 0.0);
  double tol = 8.0*EPS32D*fmax(dmax, zmax);
  int K = 0, ndefl = 0, pj = -1;
  for (int j = 0; j < n; j++){
    int nj = indx[j];
    if (rho*fabs(mz[nj]) <= tol){
      defl[ndefl++] = nj;
    } else if (pj < 0){
      pj = nj;
    } else {
      double sG = mz[pj], cG = mz[nj];
      double tau = sqrt(cG*cG + sG*sG);
      double tdf = md[nj] - md[pj];
      double c = cG/tau, s = -sG/tau;
      if (fabs(tdf*c*s) <= tol){
        mz[nj] = tau; mz[pj] = 0.0;
        if (ln < n){
          double x = Zt[(size_t)(base+ln)*AST + base+pj];
          double y = Zt[(size_t)(base+ln)*AST + base+nj];
          Zt[(size_t)(base+ln)*AST + base+pj] = c*x + s*y;
          Zt[(size_t)(base+ln)*AST + base+nj] = c*y - s*x;
        }
        double t2 = md[pj]*c*c + md[nj]*s*s;
        double t3 = md[pj]*s*s + md[nj]*c*c;
        md[nj] = t3; md[pj] = t2;
        defl[ndefl++] = pj;
        pj = nj;
      } else {
        sec[K] = pj; dl[K] = md[pj]; wz[K] = mz[pj]; K++;
        pj = nj;
      }
    }
  }
  if (pj >= 0){ sec[K] = pj; dl[K] = md[pj]; wz[K] = mz[pj]; K++; }
  double wsum2 = wsumd((ln < K) ? wz[ln]*wz[ln] : 0.0);
  if (ln < K){
    double lo = dl[ln];
    double hi = (ln < K-1) ? dl[ln+1] : (dl[K-1] + rho*wsum2);
    for (int it = 0; it < 120; it++){
      double mid = 0.5*(lo+hi);
      if (!(mid > lo) || !(mid < hi)) break;
      double fv = 1.0;
      for (int i2 = 0; i2 < K; i2++) fv += rho*wz[i2]*wz[i2]/(dl[i2]-mid);
      if (fv < 0.0) lo = mid; else hi = mid;
    }
    double lj = 0.5*(lo+hi);
    if (!(lj > dl[ln])) lj = nextafter(dl[ln], 1.0e300);
    lam[ln] = lj;
  }
  if (ln < K){
    double di = dl[ln];
    double prod = lam[K-1] - di;
    for (int j2 = 0; j2 < ln; j2++)   prod *= (lam[j2]-di)/(dl[j2]-di);
    for (int j2 = ln; j2 < K-1; j2++) prod *= (lam[j2]-di)/(dl[j2+1]-di);
    zh[ln] = copysign(sqrt(fabs(prod)), wz[ln]);
  }
  for (int j = 0; j < K; j++){
    double ui = (ln < K) ? zh[ln]/(dl[ln]-lam[j]) : 0.0;
    double nrm = sqrt(wsumd(ui*ui));
    su[ln] = ui/nrm;
    if (ln < n){
      double acc = 0.0;
      for (int i2 = 0; i2 < K; i2++)
        acc += Zt[(size_t)(base+ln)*AST + base + sec[i2]]*su[i2];
      Ttp[(size_t)ln*AST + j] = acc;
    }
    ev[j] = lam[j];
  }
  for (int j = 0; j < ndefl; j++){
    int cj = defl[j];
    if (ln < n) Ttp[(size_t)ln*AST + K + j] = Zt[(size_t)(base+ln)*AST + base + cj];
    ev[K+j] = md[cj];
  }
  if (ln < n){
    double di = ev[ln]; int r = 0;
    for (int j2 = 0; j2 < n; j2++){
      double dj = ev[j2];
      if (dj < di || (dj == di && j2 < ln)) r++;
    }
    prm[r] = ln;
  }
  if (ln < n){
    for (int c2 = 0; c2 < n; c2++)
      Zt[(size_t)(base+ln)*AST + base + c2] = Ttp[(size_t)ln*AST + prm[c2]];
    s_d[base+ln] = ev[prm[ln]];
  }
}

// 256-thread dc_merge (top).
__device__ void dc_merge(int base, int n1, int n2, double rho_in, int tid,
    double* s_d, double* Zt, double* Tt,
    double* md, double* mz, double* dl, double* wz, double* lam, double* zh,
    double* ev, double* su4, int* indx, int* sec, int* defl, int* prm,
    int* sKn){
  const int ln = tid & 63, w = tid >> 6;
  int n = n1 + n2;
  double zv = 0.0;
  if (ln < n){
    if (ln < n1) zv = Zt[(size_t)(base+n1-1)*AST + base + ln];
    else         zv = Zt[(size_t)(base+n1)*AST + base + ln];
    if (rho_in < 0.0 && ln >= n1) zv = -zv;
  }
  zv *= 0.70710678118654752440;
  mz[ln] = (ln < n) ? zv : 0.0;
  md[ln] = (ln < n) ? s_d[base+ln] : 0.0;
  __syncthreads();
  double rho = fabs(2.0*rho_in);
  if (tid == 0){
    int i1 = 0, i2 = n1, k = 0;
    while (i1 < n1 && i2 < n){
      if (md[i2] < md[i1]) indx[k++] = i2++; else indx[k++] = i1++;
    }
    while (i1 < n1) indx[k++] = i1++;
    while (i2 < n)  indx[k++] = i2++;
  }
  __syncthreads();
  double dmax = wmaxd((ln<n) ? fabs(md[ln]) : 0.0);
  double zmax = wmaxd((ln<n) ? fabs(mz[ln]) : 0.0);
  double tol = 8.0*EPS32D*fmax(dmax, zmax);
  if (w == 0){
    int K = 0, ndefl = 0, pj = -1;
    for (int j = 0; j < n; j++){
      int nj = indx[j];
      if (rho*fabs(mz[nj]) <= tol){
        defl[ndefl++] = nj;
      } else if (pj < 0){
        pj = nj;
      } else {
        double sG = mz[pj], cG = mz[nj];
        double tau = sqrt(cG*cG + sG*sG);
        double tdf = md[nj] - md[pj];
        double c = cG/tau, s = -sG/tau;
        if (fabs(tdf*c*s) <= tol){
          mz[nj] = tau; mz[pj] = 0.0;
          if (ln < n){
            double x = Zt[(size_t)(base+ln)*AST + base+pj];
            double y = Zt[(size_t)(base+ln)*AST + base+nj];
            Zt[(size_t)(base+ln)*AST + base+pj] = c*x + s*y;
            Zt[(size_t)(base+ln)*AST + base+nj] = c*y - s*x;
          }
          double t2 = md[pj]*c*c + md[nj]*s*s;
          double t3 = md[pj]*s*s + md[nj]*c*c;
          md[nj] = t3; md[pj] = t2;
          defl[ndefl++] = pj;
          pj = nj;
        } else {
          sec[K] = pj; dl[K] = md[pj]; wz[K] = mz[pj]; K++;
          pj = nj;
        }
      }
    }
    if (pj >= 0){ sec[K] = pj; dl[K] = md[pj]; wz[K] = mz[pj]; K++; }
    if (ln == 0){ sKn[0] = K; sKn[1] = ndefl; }
  }
  __syncthreads();
  const int K = sKn[0], ndefl = sKn[1];
  double wsum2 = wsumd((ln < K) ? wz[ln]*wz[ln] : 0.0);
  {
    bool conv = (ln >= K);
    double lo = 0.0, hi = 0.0;
    if (!conv){
      lo = dl[ln];
      hi = (ln < K-1) ? dl[ln+1] : (dl[K-1] + rho*wsum2);
    }
    const int i2lo = w*16;
    for (int it = 0; it < 120; it++){
      double mid = 0.0;
      if (!conv){
        mid = 0.5*(lo+hi);
        if (!(mid > lo) || !(mid < hi)) conv = true;
      }
      double fp = 0.0;
      if (!conv){
        int i2hi = i2lo + 16; if (i2hi > K) i2hi = K;
        for (int i2 = i2lo; i2 < i2hi; i2++)
          fp += rho*wz[i2]*wz[i2]/(dl[i2]-mid);
      }
      const int p = (it & 1)*256;
      su4[p + w*64 + ln] = fp;
      int alldone = __syncthreads_count(conv ? 1 : 0);
      if (alldone == 256) break;
      if (!conv){
        double fv = 1.0 + su4[p+ln] + su4[p+64+ln] + su4[p+128+ln] + su4[p+192+ln];
        if (fv < 0.0) lo = mid; else hi = mid;
      }
    }
    if (ln < K){
      double lj = 0.5*(lo+hi);
      if (!(lj > dl[ln])) lj = nextafter(dl[ln], 1.0e300);
      lam[ln] = lj;
    }
  }
  __syncthreads();
  if (ln < K){
    double di = dl[ln];
    double prod = lam[K-1] - di;
    for (int j2 = 0; j2 < ln; j2++)   prod *= (lam[j2]-di)/(dl[j2]-di);
    for (int j2 = ln; j2 < K-1; j2++) prod *= (lam[j2]-di)/(dl[j2+1]-di);
    zh[ln] = copysign(sqrt(fabs(prod)), wz[ln]);
  }
  __syncthreads();
  for (int j = w; j < K; j += 4){
    double ui = (ln < K) ? zh[ln]/(dl[ln]-lam[j]) : 0.0;
    double nrm = sqrt(wsumd(ui*ui));
    su4[w*64 + ln] = ui/nrm;
    if (ln < n){
      double acc = 0.0;
      for (int i2 = 0; i2 < K; i2++)
        acc += Zt[(size_t)(base+ln)*AST + base + sec[i2]]*su4[w*64 + i2];
      Tt[(size_t)ln*AST + j] = acc;
    }
    if (ln == 0) ev[j] = lam[j];
  }
  __syncthreads();
  for (int j = 0; j < ndefl; j++){
    int cj = defl[j];
    if (ln < n) Tt[(size_t)ln*AST + K + j] = Zt[(size_t)(base+ln)*AST + base + cj];
    if (ln == 0) ev[K+j] = md[cj];
  }
  __syncthreads();
  if (w == 0 && ln < n){
    double di = ev[ln]; int r = 0;
    for (int j2 = 0; j2 < n; j2++){
      double dj = ev[j2];
      if (dj < di || (dj == di && j2 < ln)) r++;
    }
    prm[r] = ln;
  }
  __syncthreads();
  if (ln < n){
    for (int c2 = 0; c2 < n; c2++)
      Zt[(size_t)(base+ln)*AST + base + c2] = Tt[(size_t)ln*AST + prm[c2]];
  }
  if (ln == 0){ for (int c2 = 0; c2 < n; c2++) s_d[base+c2] = ev[prm[c2]]; }
  __syncthreads();
}

// ---------------- eigensolver, 256 threads / 4 waves -----------------------
__global__ __launch_bounds__(256) void k_eig(const float* __restrict__ covg,
                                             float* __restrict__ Pg){
  int u = blockIdx.x, tid = threadIdx.x;
  const int ln = tid & 63, w = tid >> 6;
  extern __shared__ double dsm[];
  double* A  = dsm;                  // [64][65]
  double* Qh = dsm + 4160;
  double* Zt = dsm + 8320;
  double* Tt = dsm + 12480;
  __shared__ double s_d[64], s_e[64], s_tau[64], s_v[64], s_w[64];
  __shared__ double md[64], mz[64], dl[64], wz[64], lam[64], zh[64], ev[64];
  __shared__ double su4[2*4*64];
  __shared__ double z16a[4*272];
  __shared__ int indx[64], sec[64], defl[64], prm[64], sKn[2];

  for (int n = tid; n < 4096; n += 256)
    A[(n >> 6)*AST + (n & 63)] = (double)covg[(size_t)u*4096 + n];
  __syncthreads();

  for (int i = 0; i < 63; i++){
    double alpha = A[(size_t)(i+1)*AST + i];
    double xv = (ln >= i+2) ? A[(size_t)ln*AST + i] : 0.0;
    double xnorm2 = wsumd(xv*xv);
    if (xnorm2 == 0.0){
      if (tid == 0){ s_e[i] = alpha; s_tau[i] = 0.0; }
    } else {
      double beta = -copysign(sqrt(alpha*alpha + xnorm2), alpha);
      double taui = (beta - alpha)/beta;
      double sc = 1.0/(alpha - beta);
      s_v[ln] = (ln == i+1) ? 1.0 : ((ln >= i+2) ? A[(size_t)ln*AST+i]*sc : 0.0);
      __syncthreads();
      if (ln >= i+2) A[(size_t)ln*AST+i] = s_v[ln];
      double wr = 0.0;
      if (ln >= i+1){
        for (int c2 = i+1; c2 < 64; c2++){
          double av = (ln >= c2) ? A[(size_t)ln*AST+c2] : A[(size_t)c2*AST+ln];
          wr += av*s_v[c2];
        }
        wr *= taui;
      }
      double dotwv = wsumd((ln >= i+1) ? wr*s_v[ln] : 0.0);
      double alp2 = -0.5*taui*dotwv;
      wr += alp2*s_v[ln];
      s_w[ln] = (ln >= i+1) ? wr : 0.0;
      __syncthreads();
      if (ln >= i+1){
        for (int c2 = i+1; c2 <= ln; c2++)
          if ((c2 & 3) == w)
            A[(size_t)ln*AST+c2] -= s_v[ln]*s_w[c2] + s_w[ln]*s_v[c2];
      }
      if (tid == 0){ s_e[i] = beta; s_tau[i] = taui; }
    }
    __syncthreads();
  }
  if (w == 0) s_d[ln] = A[(size_t)ln*AST+ln];
  __syncthreads();

  for (int n = tid; n < 4160; n += 256) Qh[n] = 0.0;
  __syncthreads();
  if (w == 0) Qh[(size_t)ln*AST+ln] = 1.0;
  __syncthreads();
  for (int i = 62; i >= 0; i--){
    double taui = s_tau[i];
    if (taui != 0.0){
      s_v[ln] = (ln == i+1) ? 1.0 : ((ln >= i+2) ? A[(size_t)ln*AST+i] : 0.0);
      __syncthreads();
      double dj = 0.0;
      for (int r2 = i+1; r2 < 64; r2++) dj += s_v[r2]*Qh[(size_t)r2*AST+ln];
      dj *= taui;
      for (int r2 = i+1; r2 < 64; r2++)
        if ((r2 & 3) == w)
          Qh[(size_t)r2*AST+ln] -= s_v[r2]*dj;
    }
    __syncthreads();
  }

  double rho_a = s_e[15], rho_b = s_e[47], rho_top = s_e[31];
  if (tid == 0){
    s_d[15] -= fabs(rho_a);   s_d[16] -= fabs(rho_a);
    s_d[31] -= fabs(rho_top); s_d[32] -= fabs(rho_top);
    s_d[47] -= fabs(rho_b);   s_d[48] -= fabs(rho_b);
  }
  for (int n = tid; n < 4160; n += 256) Zt[n] = 0.0;
  __syncthreads();
  dsteqr16_(w*16, s_d, s_e, &z16a[w*272], ln,
            &su4[w*64], Tt + (size_t)w*1040, &indx[w*16]);
  if (ln < 16){
    for (int j = 0; j < 16; j++)
      Zt[(size_t)(w*16+ln)*AST + w*16 + j] = z16a[w*272 + ln*17+j];
  }
  __syncthreads();

  if (w == 0)
    dc_merge1(0, 16, 16, rho_a, ln, s_d, Zt, Tt,
              md, mz, dl, wz, lam, zh, ev, su4,
              indx, sec, defl, prm);
  else if (w == 1)
    dc_merge1(32, 16, 16, rho_b, ln, s_d, Zt, Tt + (size_t)32*AST,
              md+32, mz+32, dl+32, wz+32, lam+32, zh+32, ev+32, su4+64,
              indx+32, sec+32, defl+32, prm+32);
  __syncthreads();

  dc_merge(0, 32, 32, rho_top, tid, s_d, Zt, Tt, md, mz, dl, wz, lam, zh, ev, su4, indx, sec, defl, prm, sKn);

  for (int nn = w; nn < 16; nn += 4){
    double acc = 0.0;
    for (int k = 0; k < 64; k++)
      acc += Qh[(size_t)ln*AST+k]*Zt[(size_t)k*AST + (63-nn)];
    Pg[(size_t)u*1024 + ln*16 + nn] = (float)acc;
  }
}

// ---------------- input layer norm -> xnT[t][e][b] ----------------
__global__ void k_ln_in(const float* __restrict__ x, const float* __restrict__ g,
                        const float* __restrict__ be, float* __restrict__ xnT){
  int bid = blockIdx.x; int s = bid >> 5, b = bid & 31;
  int tid = threadIdx.x;
  const float* row = x + ((size_t)(s*BB + b))*EE;
  __shared__ float r1[256], r2[256];
  float su = 0.f, sq = 0.f;
  for (int e = tid; e < EE; e += 256){ float v = row[e]; su += v; sq += v*v; }
  r1[tid] = su; r2[tid] = sq; __syncthreads();
  for (int st = 128; st > 0; st >>= 1){
    if (tid < st){ r1[tid] += r1[tid+st]; r2[tid] += r2[tid+st]; }
    __syncthreads();
  }
  float mu  = r1[0] * (1.0f/EE);
  float var = r2[0] * (1.0f/EE) - mu*mu;
  float rstd = rsqrtf(var + EPSF);
  for (int e = tid; e < EE; e += 256){
    float v = (row[e]-mu)*rstd*g[e] + be[e];
    xnT[((size_t)s*EE + e)*BB + b] = v;
  }
}

// ---------------- transpose Whh -> WhhT[d][k][r] ----------------
__global__ void k_whht(const float* __restrict__ Whh_f, const float* __restrict__ Whh_b,
                       float* __restrict__ WhhT){
  int d  = blockIdx.z;
  const float* Whh = d ? Whh_b : Whh_f;
  int rt = blockIdx.x*32, kt = blockIdx.y*32;
  int tx = threadIdx.x & 31, ty = threadIdx.x >> 5;
  __shared__ float tile[32][33];
  for (int i = ty; i < 32; i += 8)
    tile[i][tx] = Whh[(size_t)(rt+i)*HH + kt+tx];
  __syncthreads();
  for (int i = ty; i < 32; i += 8)
    WhhT[((size_t)d*HH + kt+i)*G4 + rt+tx] = tile[tx][i];
}

__global__ void k_zero(float* __restrict__ p, int n){
  int i = blockIdx.x*blockDim.x + threadIdx.x;
  if (i < n) p[i] = 0.f;
}

// ---------------- xg chunk GEMM: xg[tl][r][b] = Wih_d @ xn[tsrc] ------------
__global__ __launch_bounds__(256) void k_xg(const float* __restrict__ xnT,
        const float* __restrict__ Wih_f, const float* __restrict__ Wih_b,
        float* __restrict__ xg, int* __restrict__ cnt, int c){
  if (blockIdx.x == 0 && blockIdx.y == 0 && threadIdx.x < 16)
    __hip_atomic_store(&cnt[threadIdx.x*16], 0, __ATOMIC_RELAXED, __HIP_MEMORY_SCOPE_AGENT);
  int nb = blockIdx.x, rb = blockIdx.y;
  int d = rb >> 5, rloc0 = (rb & 31)*128;
  const float* Wih = d ? Wih_b : Wih_f;
  int tid = threadIdx.x;
  int tx = tid & 15, ty = tid >> 4;
  __shared__ float Al[16*132];
  __shared__ float Bl[16*132];
  float acc[8][8];
  #pragma unroll
  for (int i = 0; i < 8; i++)
    #pragma unroll
    for (int j = 0; j < 8; j++) acc[i][j] = 0.f;
  for (int kc = 0; kc < EE; kc += 16){
    #pragma unroll
    for (int j = 0; j < 8; j++){
      int idx = tid + j*256;
      int n = idx & 127, k = idx >> 7;
      int tglob = c*TCHUNK + nb*4 + (n >> 5);
      int tsrc = d ? (SS-1-tglob) : tglob;
      Al[k*132 + n] = xnT[((size_t)tsrc*EE + kc + k)*BB + (n & 31)];
    }
    #pragma unroll
    for (int j = 0; j < 8; j++){
      int idx = tid + j*256;
      int k = idx & 15, r = idx >> 4;
      Bl[k*132 + r] = Wih[(size_t)(rloc0 + r)*EE + kc + k];
    }
    __syncthreads();
    #pragma unroll
    for (int k = 0; k < 16; k++){
      float4 a0 = *(const float4*)(&Al[k*132 + tx*4]);
      float4 a1 = *(const float4*)(&Al[k*132 + 64 + tx*4]);
      float4 b0 = *(const float4*)(&Bl[k*132 + ty*4]);
      float4 b1 = *(const float4*)(&Bl[k*132 + 64 + ty*4]);
      float av[8] = {a0.x,a0.y,a0.z,a0.w,a1.x,a1.y,a1.z,a1.w};
      float bv[8] = {b0.x,b0.y,b0.z,b0.w,b1.x,b1.y,b1.z,b1.w};
      #pragma unroll
      for (int i = 0; i < 8; i++)
        #pragma unroll
        for (int j2 = 0; j2 < 8; j2++) acc[i][j2] += av[i]*bv[j2];
    }
    __syncthreads();
  }
  #pragma unroll
  for (int j = 0; j < 8; j++){
    int r = rloc0 + ((j < 4) ? (ty*4 + j) : (64 + ty*4 + j - 4));
    #pragma unroll
    for (int ig = 0; ig < 2; ig++){
      int n0 = ig*64 + tx*4;
      int tl = nb*4 + (n0 >> 5), b = n0 & 31;
      float4 o = make_float4(acc[ig*4+0][j], acc[ig*4+1][j], acc[ig*4+2][j], acc[ig*4+3][j]);
      *(float4*)(&xg[(((size_t)tl*8192) + d*G4 + r)*BB + b]) = o;
    }
  }
}

// ---------------- persistent-chunk LSTM: XCD-partitioned directions ---------
// 256 blocks x 512 thr. Block -> XCD is (heuristically) blk%8: derive
// d = (blk&7)>>2 so each direction's 128 blocks occupy 4 XCDs (shorter
// h-exchange and barrier fabric hops). lid = (blk>>3)*4 + (blk&3) is a
// bijection 0..127 within the direction. Correctness does not depend on
// the XCD mapping. Wave = disjoint K-slice; binary-tree LDS reduction.
__global__ __launch_bounds__(512) void k_lstm(
    const float* __restrict__ WhhT,
    const float* __restrict__ bih_f, const float* __restrict__ bhh_f,
    const float* __restrict__ bih_b, const float* __restrict__ bhh_b,
    const float* __restrict__ xg, float* __restrict__ hbuf,
    float* __restrict__ cT, float* __restrict__ hs,
    int* __restrict__ cnt, int c)
{
  extern __shared__ float lsm[];
  float* Wl  = lsm;                 // [8][128][32]
  float* red = lsm + 32768;         // [4][16][64]
  float* gl  = lsm + 36864;         // [32][36]
  float* cls = lsm + 38016;         // [8][32]

  const int blk = blockIdx.x;
  const int xcd = blk & 7;
  const int d   = xcd >> 2;                      // dirs on disjoint XCD halves
  const int lid = ((blk >> 3) << 2) | (xcd & 3); // 0..127 within direction
  const int j0  = lid * 8;
  const int tid = threadIdx.x;
  const int ln  = tid & 63;
  const int w   = tid >> 6;          // wave = K-slice of 128 rows
  const int cg  = ln >> 3;           // col quad 0..7
  const int bg  = ln & 7;            // b quad 0..7
  const int b0  = bg * 4;
  const int cbase = cg * 4;

  const float* bih = d ? bih_b : bih_f;
  const float* bhh = d ? bhh_b : bhh_f;
  const float* WT_d = WhhT + (size_t)d * HH * G4;

  // ---- stage W slice into LDS (once per chunk): Wl[k>>7][k&127][c] ----
  {
    const int cs = tid & 31;
    const int ks = tid >> 5;         // 0..15
    const int g  = cs >> 3, jj = cs & 7;
    const size_t rglob = (size_t)g*HH + j0 + jj;
    for (int kk = 0; kk < 64; kk++){
      int k = kk*16 + ks;
      Wl[(k >> 7)*4096 + (k & 127)*32 + cs] = WT_d[(size_t)k*G4 + rglob];
    }
  }

  const int pjj = (tid >> 5) & 7, pb = tid & 31;
  float pbias[4];
  if (tid < 256){
    cls[pjj*32 + pb] = cT[((size_t)d*HH + j0 + pjj)*BB + pb];
    #pragma unroll
    for (int g2 = 0; g2 < 4; g2++)
      pbias[g2] = bih[g2*HH + j0 + pjj] + bhh[g2*HH + j0 + pjj];
  }
  __syncthreads();

  for (int tl = 0; tl < TCHUNK; tl++){
    const int s = c*TCHUNK + tl;
    const float* hprev = hbuf + ((size_t)((s & 1)*2 + d))*HH*BB;
    float*       hnext = hbuf + ((size_t)(((s+1) & 1)*2 + d))*HH*BB;

    float xgv[4] = {0.f,0.f,0.f,0.f};
    if (tid < 256){
      const size_t xbase = ((size_t)tl*8192 + (size_t)d*G4)*BB;
      #pragma unroll
      for (int g2 = 0; g2 < 4; g2++)
        xgv[g2] = xg[xbase + (size_t)(g2*HH + j0 + pjj)*BB + pb];
    }

    float acc[4][4];
    #pragma unroll
    for (int i = 0; i < 4; i++)
      #pragma unroll
      for (int j = 0; j < 4; j++) acc[i][j] = 0.f;

    {
      const float* hp = hprev + (size_t)(w*128)*BB + b0;
      const float* wrow = &Wl[w*4096 + cbase];
      for (int ib = 0; ib < 128; ib += 16){
        float4 hv[16];
        #pragma unroll
        for (int u = 0; u < 16; u++)
          hv[u] = *(const float4*)(hp + (size_t)(ib+u)*BB);
        #pragma unroll
        for (int u = 0; u < 16; u++){
          float4 wv = *(const float4*)(wrow + (ib+u)*32);
          acc[0][0] += wv.x*hv[u].x; acc[0][1] += wv.x*hv[u].y; acc[0][2] += wv.x*hv[u].z; acc[0][3] += wv.x*hv[u].w;
          acc[1][0] += wv.y*hv[u].x; acc[1][1] += wv.y*hv[u].y; acc[1][2] += wv.y*hv[u].z; acc[1][3] += wv.y*hv[u].w;
          acc[2][0] += wv.z*hv[u].x; acc[2][1] += wv.z*hv[u].y; acc[2][2] += wv.z*hv[u].z; acc[2][3] += wv.z*hv[u].w;
          acc[3][0] += wv.w*hv[u].x; acc[3][1] += wv.w*hv[u].y; acc[3][2] += wv.w*hv[u].z; acc[3][3] += wv.w*hv[u].w;
        }
      }
    }
    // ---- fixed binary tree over waves: ((0+4)+(2+6)) + ((1+5)+(3+7)) ----
    if (w >= 4){
      float* rp = &red[(w-4)*1024];
      #pragma unroll
      for (int i = 0; i < 4; i++)
        #pragma unroll
        for (int j = 0; j < 4; j++) rp[(i*4+j)*64 + ln] = acc[i][j];
    }
    __syncthreads();
    if (w < 4){
      const float* rp = &red[w*1024];
      #pragma unroll
      for (int i = 0; i < 4; i++)
        #pragma unroll
        for (int j = 0; j < 4; j++) acc[i][j] += rp[(i*4+j)*64 + ln];
    }
    if (w == 2 || w == 3){
      float* rp = &red[w*1024];
      #pragma unroll
      for (int i = 0; i < 4; i++)
        #pragma unroll
        for (int j = 0; j < 4; j++) rp[(i*4+j)*64 + ln] = acc[i][j];
    }
    __syncthreads();
    if (w == 0){
      const float* rp = &red[2*1024];
      #pragma unroll
      for (int i = 0; i < 4; i++)
        #pragma unroll
        for (int j = 0; j < 4; j++) acc[i][j] += rp[(i*4+j)*64 + ln];
    }
    if (w == 1){
      const float* rp = &red[3*1024];
      float* wp = &red[1*1024];
      #pragma unroll
      for (int i = 0; i < 4; i++)
        #pragma unroll
        for (int j = 0; j < 4; j++){
          acc[i][j] += rp[(i*4+j)*64 + ln];
          wp[(i*4+j)*64 + ln] = acc[i][j];
        }
    }
    __syncthreads();
    if (w == 0){
      const float* rp = &red[1*1024];
      #pragma unroll
      for (int i = 0; i < 4; i++){
        #pragma unroll
        for (int j = 0; j < 4; j++) acc[i][j] += rp[(i*4+j)*64 + ln];
        float4 o = make_float4(acc[i][0], acc[i][1], acc[i][2], acc[i][3]);
        *(float4*)(&gl[(cbase + i)*36 + b0]) = o;
      }
    }
    __syncthreads();
    if (tid < 256){
      float gv[4];
      #pragma unroll
      for (int g2 = 0; g2 < 4; g2++)
        gv[g2] = gl[(g2*8 + pjj)*36 + pb] + pbias[g2] + xgv[g2];
      float iv = sigm(gv[0]), fv = sigm(gv[1]), ggv = tanhf(gv[2]), ov = sigm(gv[3]);
      float cv = fv*cls[pjj*32 + pb] + iv*ggv;
      cls[pjj*32 + pb] = cv;
      float h = ov*tanhf(cv);
      hnext[(size_t)(j0 + pjj)*BB + pb] = h;
      int tsv = d ? (SS-1-s) : s;
      hs[(((size_t)d*SS + tsv)*HH + j0 + pjj)*BB + pb] = h;   // [d][t][j][b]
    }
    if (tl < TCHUNK-1){
      __syncthreads();
      if (tid == 0){
        __builtin_amdgcn_fence(__ATOMIC_RELEASE, "agent");
        __hip_atomic_fetch_add(&cnt[((lid & 7) + d*8)*16], 1, __ATOMIC_RELAXED, __HIP_MEMORY_SCOPE_AGENT);
        const int target = 16*(tl+1);
        const int lbase = d*8;
        int done = 0;
        while (done < 8){
          done = 0;
          #pragma unroll
          for (int i = 0; i < 8; i++)
            done += (__hip_atomic_load(&cnt[(lbase+i)*16], __ATOMIC_RELAXED, __HIP_MEMORY_SCOPE_AGENT) >= target);
          if (done < 8) __builtin_amdgcn_s_sleep(2);
        }
        __builtin_amdgcn_fence(__ATOMIC_ACQUIRE, "agent");
      }
      __syncthreads();
    }
  }
  __syncthreads();
  if (tid < 256)
    cT[((size_t)d*HH + j0 + pjj)*BB + pb] = cls[pjj*32 + pb];
}

// ---------------- LN(hs) + tanh(Wsq proj) -> xq[d][t][b][q] ----------------
// hs layout [d][t][j][b]
__global__ __launch_bounds__(256) void k_lnproj(const float* __restrict__ hs,
        const float* __restrict__ g_fw, const float* __restrict__ be_fw,
        const float* __restrict__ g_bk, const float* __restrict__ be_bk,
        const float* __restrict__ Wsq, const float* __restrict__ bsq,
        float* __restrict__ xq){
  int t = blockIdx.x, d = blockIdx.y;
  int tid = threadIdx.x;
  const float* gv  = d ? g_bk  : g_fw;
  const float* bev = d ? be_bk : be_fw;
  const float* hrow = hs + ((size_t)d*SS + t)*HH*BB;   // [HH][BB]
  __shared__ float red[256], red2[256];
  __shared__ float smu[32], srs[32];
  __shared__ float ln[32*132];
  __shared__ float wl[64*132];
  {
    int b = tid & 31, jg = tid >> 5;
    float s = 0.f, s2 = 0.f;
    for (int j = jg*128; j < jg*128+128; j++){
      float v = hrow[(size_t)j*BB + b];
      s += v; s2 += v*v;
    }
    red[b*8 + jg] = s; red2[b*8 + jg] = s2; __syncthreads();
    if (tid < 32){
      float a = 0.f, a2 = 0.f;
      for (int k = 0; k < 8; k++){ a += red[tid*8+k]; a2 += red2[tid*8+k]; }
      float mu = a*(1.f/HH), var = a2*(1.f/HH) - mu*mu;
      smu[tid] = mu; srs[tid] = rsqrtf(var + EPSF);
    }
    __syncthreads();
  }
  float acc[4][2] = {{0.f,0.f},{0.f,0.f},{0.f,0.f},{0.f,0.f}};
  int qg = tid & 31, bg = tid >> 5;
  int q0 = qg*2, b0g = bg*4;
  for (int jc = 0; jc < 8; jc++){
    for (int n = tid; n < 4096; n += 256){
      int b = n & 31, jj = n >> 5; int j = jc*128 + jj;
      float v = hrow[(size_t)j*BB + b];
      ln[b*132+jj] = (v - smu[b])*srs[b]*gv[j] + bev[j];
    }
    for (int n = tid; n < 8192; n += 256){
      int q = n >> 7, jj = n & 127;
      wl[q*132+jj] = Wsq[(size_t)q*HH + jc*128 + jj];
    }
    __syncthreads();
    for (int jj = 0; jj < 128; jj += 4){
      float4 w0 = *(const float4*)(&wl[q0*132+jj]);
      float4 w1 = *(const float4*)(&wl[(q0+1)*132+jj]);
      #pragma unroll
      for (int i = 0; i < 4; i++){
        float4 xv = *(const float4*)(&ln[(b0g+i)*132+jj]);
        acc[i][0] += xv.x*w0.x + xv.y*w0.y + xv.z*w0.z + xv.w*w0.w;
        acc[i][1] += xv.x*w1.x + xv.y*w1.y + xv.z*w1.z + xv.w*w1.w;
      }
    }
    __syncthreads();
  }
  #pragma unroll
  for (int i = 0; i < 4; i++)
    #pragma unroll
    for (int u = 0; u < 2; u++){
      float o = tanhf(acc[i][u] + bsq[q0+u]);
      xq[(((size_t)d*SS + t)*BB + (b0g+i))*QQ + q0 + u] = o;
    }
}

// ---------------- concat + LN + topic GEMM -> d_out topic_preds ----------------
__global__ __launch_bounds__(256) void k_topic(const float* __restrict__ xq,
        const float* __restrict__ g_sq, const float* __restrict__ be_sq,
        const float* __restrict__ Wtop, const float* __restrict__ btop,
        float* __restrict__ out){
  int t = blockIdx.x; int tid = threadIdx.x;
  __shared__ float xc[32*132];
  __shared__ float wl[16*520];
  __shared__ float red[256], red2[256];
  __shared__ float smu[32], srs[32];
  for (int n = tid; n < 4096; n += 256){
    int b = n >> 7, q = n & 127;
    float v = (q < 64) ? xq[(((size_t)0*SS + t)*BB + b)*QQ + q]
                       : xq[(((size_t)1*SS + t)*BB + b)*QQ + (q-64)];
    xc[b*132+q] = v;
  }
  __syncthreads();
  {
    int b = tid >> 3, sl = tid & 7;
    float s = 0.f, s2 = 0.f;
    for (int k = 0; k < 16; k++){ float v = xc[b*132 + sl*16 + k]; s += v; s2 += v*v; }
    red[tid] = s; red2[tid] = s2; __syncthreads();
    if (tid < 32){
      float a = 0.f, a2 = 0.f;
      for (int k = 0; k < 8; k++){ a += red[tid*8+k]; a2 += red2[tid*8+k]; }
      float mu = a*(1.f/128.f), var = a2*(1.f/128.f) - mu*mu;
      smu[tid] = mu; srs[tid] = rsqrtf(var + EPSF);
    }
    __syncthreads();
    for (int n = tid; n < 4096; n += 256){
      int b2 = n >> 7, q = n & 127;
      xc[b2*132+q] = (xc[b2*132+q]-smu[b2])*srs[b2]*g_sq[q] + be_sq[q];
    }
    __syncthreads();
  }
  int og = tid & 63, bg = tid >> 6;
  int o0 = og*8, b0 = bg*8;
  float acc[8][8];
  #pragma unroll
  for (int i = 0; i < 8; i++)
    #pragma unroll
    for (int j = 0; j < 8; j++) acc[i][j] = 0.f;
  for (int kc = 0; kc < 128; kc += 16){
    for (int n = tid; n < 8192; n += 256){
      int o = n >> 4, kk = n & 15;
      wl[kk*520 + o] = Wtop[(size_t)o*128 + kc + kk];
    }
    __syncthreads();
    #pragma unroll
    for (int kk = 0; kk < 16; kk++){
      float4 w0 = *(const float4*)(&wl[kk*520+o0]);
      float4 w1 = *(const float4*)(&wl[kk*520+o0+4]);
      float wv[8] = {w0.x,w0.y,w0.z,w0.w,w1.x,w1.y,w1.z,w1.w};
      int k = kc + kk;
      #pragma unroll
      for (int bi = 0; bi < 8; bi++){
        float xv = xc[(b0+bi)*132 + k];
        #pragma unroll
        for (int oi = 0; oi < 8; oi++) acc[bi][oi] += xv*wv[oi];
      }
    }
    __syncthreads();
  }
  #pragma unroll
  for (int bi = 0; bi < 8; bi++){
    int b = b0 + bi;
    #pragma unroll
    for (int oi = 0; oi < 8; oi++)
      out[((size_t)t*BB + b)*TTOP + o0 + oi] = acc[bi][oi] + btop[o0+oi];
  }
}

// ---------------- per-(dir,batch): mean, center, covariance ----------------
__global__ __launch_bounds__(256) void k_pca1(const float* __restrict__ xq,
        float* __restrict__ cmat, float* __restrict__ covg){
  int u = blockIdx.x; int d = u >> 5, b = u & 31;
  int tid = threadIdx.x;
  __shared__ float red[256];
  __shared__ float smq[64];
  {
    int q = tid & 63, tg = tid >> 6;
    float s = 0.f;
    for (int t2 = tg*64; t2 < tg*64+64; t2++)
      s += xq[(((size_t)d*SS + t2)*BB + b)*QQ + q];
    red[tid] = s; __syncthreads();
    if (tid < 64) smq[tid] = (red[tid]+red[tid+64]+red[tid+128]+red[tid+192])*(1.f/SS);
    __syncthreads();
  }
  float* cm = cmat + (size_t)u*SS*QQ;
  for (int n = tid; n < SS*QQ; n += 256){
    int t2 = n >> 6, q = n & 63;
    cm[n] = xq[(((size_t)d*SS + t2)*BB + b)*QQ + q] - smq[q];
  }
  __syncthreads();
  {
    int pg = (tid & 15)*4, qg = (tid >> 4)*4;
    float a[4][4] = {{0}};
    for (int t2 = 0; t2 < SS; t2++){
      const float* cr = cm + (size_t)t2*QQ;
      float4 cp = *(const float4*)(cr+pg);
      float4 cq = *(const float4*)(cr+qg);
      float pv[4] = {cp.x,cp.y,cp.z,cp.w}, qv[4] = {cq.x,cq.y,cq.z,cq.w};
      #pragma unroll
      for (int i = 0; i < 4; i++)
        #pragma unroll
        for (int j2 = 0; j2 < 4; j2++) a[i][j2] += pv[i]*qv[j2];
    }
    #pragma unroll
    for (int i = 0; i < 4; i++)
      #pragma unroll
      for (int j2 = 0; j2 < 4; j2++)
        covg[(size_t)u*4096 + (pg+i)*64 + qg+j2] = a[i][j2]*(1.f/SS);
  }
}

// ---------------- project + smooth + adjacent-cos ----------------
__global__ __launch_bounds__(256) void k_pca2(const float* __restrict__ cmat,
        const float* __restrict__ Pg, const float* __restrict__ kern,
        float* __restrict__ cosb){
  int u = blockIdx.x; int tid = threadIdx.x;
  __shared__ float sP[1024];
  __shared__ float sE[4096];
  __shared__ float sY[4096];
  __shared__ float kb[121];
  __shared__ float nn2[256];
  if (tid < 121) kb[tid] = kern[tid];
  for (int n = tid; n < 1024; n += 256) sP[n] = Pg[(size_t)u*1024 + n];
  __syncthreads();
  const float* cm = cmat + (size_t)u*SS*QQ;
  for (int m = tid; m < SS*NPC; m += 256){
    int t2 = m >> 4, n = m & 15;
    const float* cr = cm + (size_t)t2*QQ;
    float acc = 0.f;
    for (int i = 0; i < 64; i++) acc += cr[i]*sP[i*16+n];
    sE[m] = acc;
  }
  __syncthreads();
  for (int m = tid; m < SS*NPC; m += 256){
    int t2 = m >> 4, n = m & 15;
    float acc = 0.f;
    for (int a2 = 0; a2 < 11; a2++){
      int ta = t2 + a2 - 5;
      if (ta < 0 || ta >= SS) continue;
      #pragma unroll
      for (int b2 = 0; b2 < 11; b2++){
        int nb = n + b2 - 5;
        if (nb < 0 || nb >= NPC) continue;
        acc += kb[a2*11+b2]*sE[ta*16+nb];
      }
    }
    sY[m] = acc;
  }
  __syncthreads();
  {
    float acc = 0.f;
    #pragma unroll
    for (int n = 0; n < 16; n++){ float v = sY[tid*16+n]; acc += v*v; }
    nn2[tid] = acc;
  }
  __syncthreads();
  if (tid < 255){
    float num = 0.f;
    #pragma unroll
    for (int n = 0; n < 16; n++) num += sY[tid*16+n]*sY[(tid+1)*16+n];
    cosb[(size_t)u*256 + tid] = num/(sqrtf(nn2[tid])*sqrtf(nn2[tid+1]));
  }
}

// ---------------- d = sqrt(cf*cb); pos = argmax ----------------
__global__ void k_pos(const float* __restrict__ cosb, float* __restrict__ out){
  __shared__ float mx[256];
  __shared__ int   mi[256];
  int tid = threadIdx.x;
  for (int b = 0; b < 32; b++){
    float v = -1e30f;
    if (tid < 255){
      float cf = cosb[(size_t)(b)*256 + tid];
      float cb = cosb[(size_t)(32+b)*256 + tid];
      v = sqrtf(cf*cb);
      if (isnan(v)) v = INFINITY;
    }
    mx[tid] = v; __syncthreads();
    for (int st = 128; st > 0; st >>= 1){
      if (tid < st) mx[tid] = fmaxf(mx[tid], mx[tid+st]);
      __syncthreads();
    }
    float m = mx[0]; __syncthreads();
    mi[tid] = (tid < 255 && v == m) ? tid : (1<<30);
    __syncthreads();
    for (int st = 128; st > 0; st >>= 1){
      if (tid < st) mi[tid] = min(mi[tid], mi[tid+st]);
      __syncthreads();
    }
    if (tid == 0) out[(size_t)SS*BB*TTOP + b] = (float)mi[0];
    __syncthreads();
  }
}

// ---------------- launch ----------------
extern "C" void kernel_launch(void* const* d_in, const int* in_sizes, int n_in,
                              void* d_out, int out_size, void* d_ws, size_t ws_size,
                              hipStream_t stream){
  (void)in_sizes; (void)n_in; (void)out_size; (void)ws_size;
  const float* x      = (const float*)d_in[0];
  const float* Wih_f  = (const float*)d_in[1];
  const float* Whh_f  = (const float*)d_in[2];
  const float* bih_f  = (const float*)d_in[3];
  const float* bhh_f  = (const float*)d_in[4];
  const float* Wih_b  = (const float*)d_in[5];
  const float* Whh_b  = (const float*)d_in[6];
  const float* bih_b  = (const float*)d_in[7];
  const float* bhh_b  = (const float*)d_in[8];
  const float* g_in   = (const float*)d_in[9];
  const float* be_in  = (const float*)d_in[10];
  const float* g_fw   = (const float*)d_in[11];
  const float* be_fw  = (const float*)d_in[12];
  const float* g_bk   = (const float*)d_in[13];
  const float* be_bk  = (const float*)d_in[14];
  const float* g_sq   = (const float*)d_in[15];
  const float* be_sq  = (const float*)d_in[16];
  const float* Wsq    = (const float*)d_in[17];
  const float* bsq    = (const float*)d_in[18];
  const float* Wtop   = (const float*)d_in[19];
  const float* btop   = (const float*)d_in[20];
  const float* gkern  = (const float*)d_in[21];

  float* ws    = (float*)d_ws;
  float* xnT   = ws + OFF_XNT;
  float* WhhT  = ws + OFF_WHHT;
  float* cT    = ws + OFF_CT;
  float* hbuf  = ws + OFF_HBUF;
  int*   cnt   = (int*)(ws + OFF_CNT);
  float* xg    = ws + OFF_XG;
  float* hs    = ws + OFF_HS;
  float* xq    = ws + OFF_XQ;
  float* cmat  = ws + OFF_CMAT;
  float* covg  = ws + OFF_COV;
  float* Pg    = ws + OFF_PG;
  float* cosb  = ws + OFF_COS;
  float* out   = (float*)d_out;

  hipFuncSetAttribute((const void*)k_eig,
                      hipFuncAttributeMaxDynamicSharedMemorySize, EIG_DYN_LDS);
  hipFuncSetAttribute((const void*)k_lstm,
                      hipFuncAttributeMaxDynamicSharedMemorySize, LSTM_DYN_LDS);

  k_zero<<<dim3(768), dim3(256), 0, stream>>>(cT, 196608);   // cT + hbuf
  k_ln_in<<<dim3(SS*BB), dim3(256), 0, stream>>>(x, g_in, be_in, xnT);
  k_whht<<<dim3(128, 32, 2), dim3(256), 0, stream>>>(Whh_f, Whh_b, WhhT);
  for (int c = 0; c < SS/TCHUNK; c++){
    k_xg<<<dim3(8, 64), dim3(256), 0, stream>>>(xnT, Wih_f, Wih_b, xg, cnt, c);
    k_lstm<<<dim3(NBLK), dim3(512), LSTM_DYN_LDS, stream>>>(WhhT, bih_f, bhh_f, bih_b, bhh_b,
                                                            xg, hbuf, cT, hs, cnt, c);
  }
  k_lnproj<<<dim3(SS,2), dim3(256), 0, stream>>>(hs, g_fw, be_fw, g_bk, be_bk, Wsq, bsq, xq);
  k_topic<<<dim3(SS), dim3(256), 0, stream>>>(xq, g_sq, be_sq, Wtop, btop, out);
  k_pca1<<<dim3(64), dim3(256), 0, stream>>>(xq, cmat, covg);
  k_eig<<<dim3(64), dim3(256), EIG_DYN_LDS, stream>>>(covg, Pg);
  k_pca2<<<dim3(64), dim3(256), 0, stream>>>(cmat, Pg, gkern, cosb);
  k_pos<<<dim3(1), dim3(256), 0, stream>>>(cosb, out);
}

// Round 17
// 7222.864 us; speedup vs baseline: 1.0719x; 1.0719x over previous
//
#include <hip/hip_runtime.h>
#include <cstdint>
#include <cstddef>

// ---------------- problem dims ----------------
#define SS   256
#define BB   32
#define EE   768
#define HH   1024
#define QQ   64
#define TTOP 512
#define NPC  16
#define G4   4096          // 4*H
#define TCHUNK 32
#define NBLK 256
#define EPSF 1e-5f

// ---------------- ws layout (floats) ----------------
#define OFF_XNT   ((size_t)0)                       // [256][768][32]   (6,291,456)
#define OFF_WHHT  ((size_t)6291456)                 // [2][1024][4096]  (8,388,608)
#define OFF_CT    ((size_t)14680064)                // [2][1024][32]    (65,536)
#define OFF_HBUF  ((size_t)14745600)                // [2][2][1024][32] (131,072)
#define OFF_CNT   ((size_t)14876672)                // barrier lines    (512)
#define OFF_XG    ((size_t)14877184)                // [32][8192][32]   (8,388,608)
#define OFF_HS    ((size_t)23265792)                // [2][256][1024][32] (16,777,216)  [j][b]
#define OFF_XQ    ((size_t)40043008)                // [2][256][32][64] (1,048,576)
// post-LSTM overlays inside XNT region (xnT dead after last k_xg):
#define OFF_CMAT  ((size_t)0)                       // [64][256][64]  (1,048,576)
#define OFF_COV   ((size_t)1048576)                 // [64][64][64]   (262,144)
#define OFF_PG    ((size_t)1310720)                 // [64][64][16]   (65,536)
#define OFF_COS   ((size_t)1376256)                 // [64][256]      (16,384)

// k_lstm dynamic LDS: Wl 8*(128*36+8)=36928 + gl[32][36]=1152 + cls 256 dwords
#define WLKS 4616
#define LSTM_DYN_LDS 153344

// k_eig: 4 matrices padded to 64x65 f64
#define AST 65
#define EIG_DYN_LDS 133120

// LAPACK f32 machine constants (branch thresholds; math in f64)
#define EPS32D    5.9604644775390625e-8
#define EPS232D   (EPS32D*EPS32D)
#define SAFMIN32D 1.1754943508222875e-38

__device__ __forceinline__ float sigm(float x){ return 1.0f/(1.0f + expf(-x)); }

__device__ __forceinline__ double wsumd(double v){
  #pragma unroll
  for (int o = 32; o; o >>= 1) v += __shfl_xor(v, o, 64);
  return v;
}
__device__ __forceinline__ double wmaxd(double v){
  #pragma unroll
  for (int o = 32; o; o >>= 1) v = fmax(v, __shfl_xor(v, o, 64));
  return v;
}
__device__ __forceinline__ void dlartg_(double f, double g, double& c, double& s, double& r){
  if (g == 0.0){ c = 1.0; s = 0.0; r = f; }
  else if (f == 0.0){ c = 0.0; s = (g >= 0.0) ? 1.0 : -1.0; r = fabs(g); }
  else {
    double d = sqrt(f*f + g*g);
    c = fabs(f)/d;
    r = copysign(d, f);
    s = g/r;
  }
}
__device__ void dlaev2_(double a, double b, double c,
                        double& rt1, double& rt2, double& cs1, double& sn1){
  double sm = a + c, df = a - c, adf = fabs(df), tb = b + b, ab = fabs(tb);
  double acmx, acmn;
  if (fabs(a) > fabs(c)){ acmx = a; acmn = c; } else { acmx = c; acmn = a; }
  double rt;
  if (adf > ab)      rt = adf*sqrt(1.0 + (ab/adf)*(ab/adf));
  else if (adf < ab) rt = ab*sqrt(1.0 + (adf/ab)*(adf/ab));
  else               rt = ab*sqrt(2.0);
  int sgn1;
  if (sm < 0.0){ rt1 = 0.5*(sm - rt); sgn1 = -1; rt2 = (acmx/rt1)*acmn - (b/rt1)*b; }
  else if (sm > 0.0){ rt1 = 0.5*(sm + rt); sgn1 = 1; rt2 = (acmx/rt1)*acmn - (b/rt1)*b; }
  else { rt1 = 0.5*rt; rt2 = -0.5*rt; sgn1 = 1; }
  double cs; int sgn2;
  if (df >= 0.0){ cs = df + rt; sgn2 = 1; } else { cs = df - rt; sgn2 = -1; }
  double acs = fabs(cs);
  if (acs > ab){ double ct = -tb/cs; sn1 = 1.0/sqrt(1.0+ct*ct); cs1 = ct*sn1; }
  else {
    if (ab == 0.0){ cs1 = 1.0; sn1 = 0.0; }
    else { double tn = -cs/tb; cs1 = 1.0/sqrt(1.0+tn*tn); sn1 = tn*cs1; }
  }
  if (sgn1 == sgn2){ double tn = cs1; cs1 = -sn1; sn1 = tn; }
}

// wave-synchronous (NO __syncthreads inside): one leaf per wave.
// tmpd: 16 dbl, tmpz: 256 dbl, rk: 16 int (per-wave scratch)
__device__ void dsteqr16_(int base, double* d, double* e, double* z16, int ln,
                          double* tmpd, double* tmpz, int* rk){
  if (ln < 16){
    #pragma unroll
    for (int j = 0; j < 16; j++) z16[ln*17+j] = (ln==j) ? 1.0 : 0.0;
  }
  const int n = 16, nm1 = 15;
  int jtot = 0; const int nmaxit = 480;
  int l1 = 0;
  while (l1 < n){
    if (l1 > 0) e[base+l1-1] = 0.0;
    int m = nm1;
    for (int mm = l1; mm < nm1; mm++){
      double tst = fabs(e[base+mm]);
      if (tst == 0.0){ m = mm; break; }
      if (tst <= (sqrt(fabs(d[base+mm]))*sqrt(fabs(d[base+mm+1])))*EPS32D){
        e[base+mm] = 0.0; m = mm; break;
      }
    }
    int l = l1, lend = m;
    l1 = m + 1;
    if (lend == l) continue;
    if (fabs(d[base+lend]) < fabs(d[base+l])){ int t = l; l = lend; lend = t; }
    if (lend > l){
      for (;;){
        int mm = lend;
        for (int k2 = l; k2 < lend; k2++){
          double tst = e[base+k2]*e[base+k2];
          if (tst <= (EPS232D*fabs(d[base+k2]))*fabs(d[base+k2+1]) + SAFMIN32D){ mm = k2; break; }
        }
        if (mm < lend) e[base+mm] = 0.0;
        double p = d[base+l];
        if (mm == l){ l++; if (l <= lend) continue; break; }
        if (mm == l+1){
          double rt1, rt2, cc, ss;
          dlaev2_(d[base+l], e[base+l], d[base+l+1], rt1, rt2, cc, ss);
          if (ln < 16){
            double x = z16[ln*17+l], y = z16[ln*17+l+1];
            z16[ln*17+l]   = cc*x + ss*y;
            z16[ln*17+l+1] = cc*y - ss*x;
          }
          d[base+l] = rt1; d[base+l+1] = rt2; e[base+l] = 0.0;
          l += 2; if (l <= lend) continue; break;
        }
        if (jtot == nmaxit) break;
        jtot++;
        double g = (d[base+l+1]-p)/(2.0*e[base+l]);
        double r = sqrt(g*g+1.0);
        g = d[base+mm] - p + e[base+l]/(g + copysign(r, g));
        double s2 = 1.0, c2 = 1.0; p = 0.0;
        for (int i = mm-1; i >= l; i--){
          double f = s2*e[base+i], b = c2*e[base+i];
          dlartg_(g, f, c2, s2, r);
          if (i != mm-1) e[base+i+1] = r;
          g = d[base+i+1] - p;
          r = (d[base+i]-g)*s2 + 2.0*c2*b;
          p = s2*r;
          d[base+i+1] = g + p;
          g = c2*r - b;
          if (ln < 16){
            double x = z16[ln*17+i], y = z16[ln*17+i+1];
            z16[ln*17+i]   = c2*x - s2*y;
            z16[ln*17+i+1] = s2*x + c2*y;
          }
        }
        d[base+l] -= p; e[base+l] = g;
      }
    } else {
      for (;;){
        int mm = lend;
        for (int k2 = l; k2 > lend; k2--){
          double tst = e[base+k2-1]*e[base+k2-1];
          if (tst <= (EPS232D*fabs(d[base+k2]))*fabs(d[base+k2-1]) + SAFMIN32D){ mm = k2; break; }
        }
        if (mm > lend) e[base+mm-1] = 0.0;
        double p = d[base+l];
        if (mm == l){ l--; if (l >= lend) continue; break; }
        if (mm == l-1){
          double rt1, rt2, cc, ss;
          dlaev2_(d[base+l-1], e[base+l-1], d[base+l], rt1, rt2, cc, ss);
          if (ln < 16){
            double x = z16[ln*17+l-1], y = z16[ln*17+l];
            z16[ln*17+l-1] = cc*x + ss*y;
            z16[ln*17+l]   = cc*y - ss*x;
          }
          d[base+l-1] = rt1; d[base+l] = rt2; e[base+l-1] = 0.0;
          l -= 2; if (l >= lend) continue; break;
        }
        if (jtot == nmaxit) break;
        jtot++;
        double g = (d[base+l-1]-p)/(2.0*e[base+l-1]);
        double r = sqrt(g*g+1.0);
        g = d[base+mm] - p + e[base+l-1]/(g + copysign(r, g));
        double s2 = 1.0, c2 = 1.0; p = 0.0;
        for (int i = mm; i <= l-1; i++){
          double f = s2*e[base+i], b = c2*e[base+i];
          dlartg_(g, f, c2, s2, r);
          if (i != mm) e[base+i-1] = r;
          g = d[base+i] - p;
          r = (d[base+i+1]-g)*s2 + 2.0*c2*b;
          p = s2*r;
          d[base+i] = g + p;
          g = c2*r - b;
          if (ln < 16){
            double x = z16[ln*17+i], y = z16[ln*17+i+1];
            z16[ln*17+i]   = c2*x + s2*y;
            z16[ln*17+i+1] = c2*y - s2*x;
          }
        }
        d[base+l] -= p; e[base+l-1] = g;
      }
    }
  }
  // rank-based stable sort (ascending); replaces selection sort
  if (ln < 16){
    double di = d[base+ln]; int r = 0;
    for (int j = 0; j < 16; j++){
      double dj = d[base+j];
      if (dj < di || (dj == di && j < ln)) r++;
    }
    rk[ln] = r;
    tmpd[r] = di;
  }
  if (ln < 16){
    for (int j = 0; j < 16; j++) tmpz[ln*16 + rk[j]] = z16[ln*17 + j];
    for (int j = 0; j < 16; j++) z16[ln*17 + j] = tmpz[ln*16 + j];
    d[base+ln] = tmpd[ln];
  }
}

// single-wave dc_merge (wave-synchronous, no barriers). Scratch slices are
// per-wave; Ttp row-base disjoint per wave. Proven round-9 arithmetic.
__device__ void dc_merge1(int base, int n1, int n2, double rho_in, int ln,
    double* s_d, double* Zt, double* Ttp,
    double* md, double* mz, double* dl, double* wz, double* lam, double* zh,
    double* ev, double* su, int* indx, int* sec, int* defl, int* prm){
  const int n = n1 + n2;
  double zv = 0.0;
  if (ln < n){
    if (ln < n1) zv = Zt[(size_t)(base+n1-1)*AST + base + ln];
    else         zv = Zt[(size_t)(base+n1)*AST + base + ln];
    if (rho_in < 0.0 && ln >= n1) zv = -zv;
  }
  zv *= 0.70710678118654752440;
  double mdv = (ln < n) ? s_d[base+ln] : 0.0;
  if (ln < n){ mz[ln] = zv; md[ln] = mdv; }
  double rho = fabs(2.0*rho_in);
  if (ln == 0){
    int i1 = 0, i2 = n1, k = 0;
    while (i1 < n1 && i2 < n){
      if (md[i2] < md[i1]) indx[k++] = i2++; else indx[k++] = i1++;
    }
    while (i1 < n1) indx[k++] = i1++;
    while (i2 < n)  indx[k++] = i2++;
  }
  double dmax = wmaxd((ln<n) ? fabs(mdv) : 0.0);
  double zmax = wmaxd((ln<n) ? fabs(zv) : 0.0);
  double tol = 8.0*EPS32D*fmax(dmax, zmax);
  int K = 0, ndefl = 0, pj = -1;
  for (int j = 0; j < n; j++){
    int nj = indx[j];
    if (rho*fabs(mz[nj]) <= tol){
      defl[ndefl++] = nj;
    } else if (pj < 0){
      pj = nj;
    } else {
      double sG = mz[pj], cG = mz[nj];
      double tau = sqrt(cG*cG + sG*sG);
      double tdf = md[nj] - md[pj];
      double c = cG/tau, s = -sG/tau;
      if (fabs(tdf*c*s) <= tol){
        mz[nj] = tau; mz[pj] = 0.0;
        if (ln < n){
          double x = Zt[(size_t)(base+ln)*AST + base+pj];
          double y = Zt[(size_t)(base+ln)*AST + base+nj];
          Zt[(size_t)(base+ln)*AST + base+pj] = c*x + s*y;
          Zt[(size_t)(base+ln)*AST + base+nj] = c*y - s*x;
        }
        double t2 = md[pj]*c*c + md[nj]*s*s;
        double t3 = md[pj]*s*s + md[nj]*c*c;
        md[nj] = t3; md[pj] = t2;
        defl[ndefl++] = pj;
        pj = nj;
      } else {
        sec[K] = pj; dl[K] = md[pj]; wz[K] = mz[pj]; K++;
        pj = nj;
      }
    }
  }
  if (pj >= 0){ sec[K] = pj; dl[K] = md[pj]; wz[K] = mz[pj]; K++; }
  double wsum2 = wsumd((ln < K) ? wz[ln]*wz[ln] : 0.0);
  if (ln < K){
    double lo = dl[ln];
    double hi = (ln < K-1) ? dl[ln+1] : (dl[K-1] + rho*wsum2);
    for (int it = 0; it < 120; it++){
      double mid = 0.5*(lo+hi);
      if (!(mid > lo) || !(mid < hi)) break;
      double fv = 1.0;
      for (int i2 = 0; i2 < K; i2++) fv += rho*wz[i2]*wz[i2]/(dl[i2]-mid);
      if (fv < 0.0) lo = mid; else hi = mid;
    }
    double lj = 0.5*(lo+hi);
    if (!(lj > dl[ln])) lj = nextafter(dl[ln], 1.0e300);
    lam[ln] = lj;
  }
  if (ln < K){
    double di = dl[ln];
    double prod = lam[K-1] - di;
    for (int j2 = 0; j2 < ln; j2++)   prod *= (lam[j2]-di)/(dl[j2]-di);
    for (int j2 = ln; j2 < K-1; j2++) prod *= (lam[j2]-di)/(dl[j2+1]-di);
    zh[ln] = copysign(sqrt(fabs(prod)), wz[ln]);
  }
  for (int j = 0; j < K; j++){
    double ui = (ln < K) ? zh[ln]/(dl[ln]-lam[j]) : 0.0;
    double nrm = sqrt(wsumd(ui*ui));
    su[ln] = ui/nrm;
    if (ln < n){
      double acc = 0.0;
      for (int i2 = 0; i2 < K; i2++)
        acc += Zt[(size_t)(base+ln)*AST + base + sec[i2]]*su[i2];
      Ttp[(size_t)ln*AST + j] = acc;
    }
    ev[j] = lam[j];
  }
  for (int j = 0; j < ndefl; j++){
    int cj = defl[j];
    if (ln < n) Ttp[(size_t)ln*AST + K + j] = Zt[(size_t)(base+ln)*AST + base + cj];
    ev[K+j] = md[cj];
  }
  // rank-based stable sort of ev
  if (ln < n){
    double di = ev[ln]; int r = 0;
    for (int j2 = 0; j2 < n; j2++){
      double dj = ev[j2];
      if (dj < di || (dj == di && j2 < ln)) r++;
    }
    prm[r] = ln;
  }
  if (ln < n){
    for (int c2 = 0; c2 < n; c2++)
      Zt[(size_t)(base+ln)*AST + base + c2] = Ttp[(size_t)ln*AST + prm[c2]];
    s_d[base+ln] = ev[prm[ln]];
  }
}

// 256-thread dc_merge (top). Bisection: fv split across waves, parity su4,
// ONE barrier per iteration. Rank-based sort.
__device__ void dc_merge(int base, int n1, int n2, double rho_in, int tid,
    double* s_d, double* Zt, double* Tt,
    double* md, double* mz, double* dl, double* wz, double* lam, double* zh,
    double* ev, double* su4, int* indx, int* sec, int* defl, int* prm,
    int* sKn){
  const int ln = tid & 63, w = tid >> 6;
  int n = n1 + n2;
  double zv = 0.0;
  if (ln < n){
    if (ln < n1) zv = Zt[(size_t)(base+n1-1)*AST + base + ln];
    else         zv = Zt[(size_t)(base+n1)*AST + base + ln];
    if (rho_in < 0.0 && ln >= n1) zv = -zv;
  }
  zv *= 0.70710678118654752440;
  mz[ln] = (ln < n) ? zv : 0.0;
  md[ln] = (ln < n) ? s_d[base+ln] : 0.0;
  __syncthreads();
  double rho = fabs(2.0*rho_in);
  if (tid == 0){
    int i1 = 0, i2 = n1, k = 0;
    while (i1 < n1 && i2 < n){
      if (md[i2] < md[i1]) indx[k++] = i2++; else indx[k++] = i1++;
    }
    while (i1 < n1) indx[k++] = i1++;
    while (i2 < n)  indx[k++] = i2++;
  }
  __syncthreads();
  double dmax = wmaxd((ln<n) ? fabs(md[ln]) : 0.0);
  double zmax = wmaxd((ln<n) ? fabs(mz[ln]) : 0.0);
  double tol = 8.0*EPS32D*fmax(dmax, zmax);
  if (w == 0){
    int K = 0, ndefl = 0, pj = -1;
    for (int j = 0; j < n; j++){
      int nj = indx[j];
      if (rho*fabs(mz[nj]) <= tol){
        defl[ndefl++] = nj;
      } else if (pj < 0){
        pj = nj;
      } else {
        double sG = mz[pj], cG = mz[nj];
        double tau = sqrt(cG*cG + sG*sG);
        double tdf = md[nj] - md[pj];
        double c = cG/tau, s = -sG/tau;
        if (fabs(tdf*c*s) <= tol){
          mz[nj] = tau; mz[pj] = 0.0;
          if (ln < n){
            double x = Zt[(size_t)(base+ln)*AST + base+pj];
            double y = Zt[(size_t)(base+ln)*AST + base+nj];
            Zt[(size_t)(base+ln)*AST + base+pj] = c*x + s*y;
            Zt[(size_t)(base+ln)*AST + base+nj] = c*y - s*x;
          }
          double t2 = md[pj]*c*c + md[nj]*s*s;
          double t3 = md[pj]*s*s + md[nj]*c*c;
          md[nj] = t3; md[pj] = t2;
          defl[ndefl++] = pj;
          pj = nj;
        } else {
          sec[K] = pj; dl[K] = md[pj]; wz[K] = mz[pj]; K++;
          pj = nj;
        }
      }
    }
    if (pj >= 0){ sec[K] = pj; dl[K] = md[pj]; wz[K] = mz[pj]; K++; }
    if (ln == 0){ sKn[0] = K; sKn[1] = ndefl; }
  }
  __syncthreads();
  const int K = sKn[0], ndefl = sKn[1];
  double wsum2 = wsumd((ln < K) ? wz[ln]*wz[ln] : 0.0);
  {
    bool conv = (ln >= K);
    double lo = 0.0, hi = 0.0;
    if (!conv){
      lo = dl[ln];
      hi = (ln < K-1) ? dl[ln+1] : (dl[K-1] + rho*wsum2);
    }
    const int i2lo = w*16;
    for (int it = 0; it < 120; it++){
      double mid = 0.0;
      if (!conv){
        mid = 0.5*(lo+hi);
        if (!(mid > lo) || !(mid < hi)) conv = true;
      }
      double fp = 0.0;
      if (!conv){
        int i2hi = i2lo + 16; if (i2hi > K) i2hi = K;
        for (int i2 = i2lo; i2 < i2hi; i2++)
          fp += rho*wz[i2]*wz[i2]/(dl[i2]-mid);
      }
      const int p = (it & 1)*256;
      su4[p + w*64 + ln] = fp;
      int alldone = __syncthreads_count(conv ? 1 : 0);
      if (alldone == 256) break;
      if (!conv){
        double fv = 1.0 + su4[p+ln] + su4[p+64+ln] + su4[p+128+ln] + su4[p+192+ln];
        if (fv < 0.0) lo = mid; else hi = mid;
      }
    }
    if (ln < K){
      double lj = 0.5*(lo+hi);
      if (!(lj > dl[ln])) lj = nextafter(dl[ln], 1.0e300);
      lam[ln] = lj;
    }
  }
  __syncthreads();
  if (ln < K){
    double di = dl[ln];
    double prod = lam[K-1] - di;
    for (int j2 = 0; j2 < ln; j2++)   prod *= (lam[j2]-di)/(dl[j2]-di);
    for (int j2 = ln; j2 < K-1; j2++) prod *= (lam[j2]-di)/(dl[j2+1]-di);
    zh[ln] = copysign(sqrt(fabs(prod)), wz[ln]);
  }
  __syncthreads();
  for (int j = w; j < K; j += 4){
    double ui = (ln < K) ? zh[ln]/(dl[ln]-lam[j]) : 0.0;
    double nrm = sqrt(wsumd(ui*ui));
    su4[w*64 + ln] = ui/nrm;
    if (ln < n){
      double acc = 0.0;
      for (int i2 = 0; i2 < K; i2++)
        acc += Zt[(size_t)(base+ln)*AST + base + sec[i2]]*su4[w*64 + i2];
      Tt[(size_t)ln*AST + j] = acc;
    }
    if (ln == 0) ev[j] = lam[j];
  }
  __syncthreads();
  for (int j = 0; j < ndefl; j++){
    int cj = defl[j];
    if (ln < n) Tt[(size_t)ln*AST + K + j] = Zt[(size_t)(base+ln)*AST + base + cj];
    if (ln == 0) ev[K+j] = md[cj];
  }
  __syncthreads();
  if (w == 0 && ln < n){
    double di = ev[ln]; int r = 0;
    for (int j2 = 0; j2 < n; j2++){
      double dj = ev[j2];
      if (dj < di || (dj == di && j2 < ln)) r++;
    }
    prm[r] = ln;
  }
  __syncthreads();
  if (ln < n){
    for (int c2 = 0; c2 < n; c2++)
      Zt[(size_t)(base+ln)*AST + base + c2] = Tt[(size_t)ln*AST + prm[c2]];
  }
  if (ln == 0){ for (int c2 = 0; c2 < n; c2++) s_d[base+c2] = ev[prm[c2]]; }
  __syncthreads();
}

// ---------------- eigensolver, 256 threads / 4 waves -----------------------
__global__ __launch_bounds__(256) void k_eig(const float* __restrict__ covg,
                                             float* __restrict__ Pg){
  int u = blockIdx.x, tid = threadIdx.x;
  const int ln = tid & 63, w = tid >> 6;
  extern __shared__ double dsm[];
  double* A  = dsm;                  // [64][65]
  double* Qh = dsm + 4160;
  double* Zt = dsm + 8320;
  double* Tt = dsm + 12480;
  __shared__ double s_d[64], s_e[64], s_tau[64], s_v[64], s_w[64];
  __shared__ double md[64], mz[64], dl[64], wz[64], lam[64], zh[64], ev[64];
  __shared__ double su4[2*4*64];
  __shared__ double z16a[4*272];
  __shared__ int indx[64], sec[64], defl[64], prm[64], sKn[2];

  for (int n = tid; n < 4096; n += 256)
    A[(n >> 6)*AST + (n & 63)] = (double)covg[(size_t)u*4096 + n];
  __syncthreads();

  // ---- dsytd2: redundant except the rank-2 update (split c2%4==w) ----
  for (int i = 0; i < 63; i++){
    double alpha = A[(size_t)(i+1)*AST + i];
    double xv = (ln >= i+2) ? A[(size_t)ln*AST + i] : 0.0;
    double xnorm2 = wsumd(xv*xv);
    if (xnorm2 == 0.0){
      if (tid == 0){ s_e[i] = alpha; s_tau[i] = 0.0; }
    } else {
      double beta = -copysign(sqrt(alpha*alpha + xnorm2), alpha);
      double taui = (beta - alpha)/beta;
      double sc = 1.0/(alpha - beta);
      s_v[ln] = (ln == i+1) ? 1.0 : ((ln >= i+2) ? A[(size_t)ln*AST+i]*sc : 0.0);
      __syncthreads();
      if (ln >= i+2) A[(size_t)ln*AST+i] = s_v[ln];
      double wr = 0.0;
      if (ln >= i+1){
        for (int c2 = i+1; c2 < 64; c2++){
          double av = (ln >= c2) ? A[(size_t)ln*AST+c2] : A[(size_t)c2*AST+ln];
          wr += av*s_v[c2];
        }
        wr *= taui;
      }
      double dotwv = wsumd((ln >= i+1) ? wr*s_v[ln] : 0.0);
      double alp2 = -0.5*taui*dotwv;
      wr += alp2*s_v[ln];
      s_w[ln] = (ln >= i+1) ? wr : 0.0;
      __syncthreads();
      if (ln >= i+1){
        for (int c2 = i+1; c2 <= ln; c2++)
          if ((c2 & 3) == w)
            A[(size_t)ln*AST+c2] -= s_v[ln]*s_w[c2] + s_w[ln]*s_v[c2];
      }
      if (tid == 0){ s_e[i] = beta; s_tau[i] = taui; }
    }
    __syncthreads();
  }
  if (w == 0) s_d[ln] = A[(size_t)ln*AST+ln];
  __syncthreads();

  // ---- sorgtr: dj redundant; column update split r2%4==w ----
  for (int n = tid; n < 4160; n += 256) Qh[n] = 0.0;
  __syncthreads();
  if (w == 0) Qh[(size_t)ln*AST+ln] = 1.0;
  __syncthreads();
  for (int i = 62; i >= 0; i--){
    double taui = s_tau[i];
    if (taui != 0.0){
      s_v[ln] = (ln == i+1) ? 1.0 : ((ln >= i+2) ? A[(size_t)ln*AST+i] : 0.0);
      __syncthreads();
      double dj = 0.0;
      for (int r2 = i+1; r2 < 64; r2++) dj += s_v[r2]*Qh[(size_t)r2*AST+ln];
      dj *= taui;
      for (int r2 = i+1; r2 < 64; r2++)
        if ((r2 & 3) == w)
          Qh[(size_t)r2*AST+ln] -= s_v[r2]*dj;
    }
    __syncthreads();
  }

  double rho_a = s_e[15], rho_b = s_e[47], rho_top = s_e[31];
  if (tid == 0){
    s_d[15] -= fabs(rho_a);   s_d[16] -= fabs(rho_a);
    s_d[31] -= fabs(rho_top); s_d[32] -= fabs(rho_top);
    s_d[47] -= fabs(rho_b);   s_d[48] -= fabs(rho_b);
  }
  for (int n = tid; n < 4160; n += 256) Zt[n] = 0.0;
  __syncthreads();
  // ---- 4 leaves, one per wave, concurrent (Tt free -> per-wave z-temp) ----
  dsteqr16_(w*16, s_d, s_e, &z16a[w*272], ln,
            &su4[w*64], Tt + (size_t)w*1040, &indx[w*16]);
  if (ln < 16){
    for (int j = 0; j < 16; j++)
      Zt[(size_t)(w*16+ln)*AST + w*16 + j] = z16a[w*272 + ln*17+j];
  }
  __syncthreads();

  // ---- 16+16 merges concurrent: wave 0 -> [0,32), wave 1 -> [32,64) ----
  if (w == 0)
    dc_merge1(0, 16, 16, rho_a, ln, s_d, Zt, Tt,
              md, mz, dl, wz, lam, zh, ev, su4,
              indx, sec, defl, prm);
  else if (w == 1)
    dc_merge1(32, 16, 16, rho_b, ln, s_d, Zt, Tt + (size_t)32*AST,
              md+32, mz+32, dl+32, wz+32, lam+32, zh+32, ev+32, su4+64,
              indx+32, sec+32, defl+32, prm+32);
  __syncthreads();

  dc_merge(0, 32, 32, rho_top, tid, s_d, Zt, Tt, md, mz, dl, wz, lam, zh, ev, su4, indx, sec, defl, prm, sKn);

  for (int nn = w; nn < 16; nn += 4){
    double acc = 0.0;
    for (int k = 0; k < 64; k++)
      acc += Qh[(size_t)ln*AST+k]*Zt[(size_t)k*AST + (63-nn)];
    Pg[(size_t)u*1024 + ln*16 + nn] = (float)acc;
  }
}

// ---------------- input layer norm -> xnT[t][e][b] ----------------
__global__ void k_ln_in(const float* __restrict__ x, const float* __restrict__ g,
                        const float* __restrict__ be, float* __restrict__ xnT){
  int bid = blockIdx.x; int s = bid >> 5, b = bid & 31;
  int tid = threadIdx.x;
  const float* row = x + ((size_t)(s*BB + b))*EE;
  __shared__ float r1[256], r2[256];
  float su = 0.f, sq = 0.f;
  for (int e = tid; e < EE; e += 256){ float v = row[e]; su += v; sq += v*v; }
  r1[tid] = su; r2[tid] = sq; __syncthreads();
  for (int st = 128; st > 0; st >>= 1){
    if (tid < st){ r1[tid] += r1[tid+st]; r2[tid] += r2[tid+st]; }
    __syncthreads();
  }
  float mu  = r1[0] * (1.0f/EE);
  float var = r2[0] * (1.0f/EE) - mu*mu;
  float rstd = rsqrtf(var + EPSF);
  for (int e = tid; e < EE; e += 256){
    float v = (row[e]-mu)*rstd*g[e] + be[e];
    xnT[((size_t)s*EE + e)*BB + b] = v;
  }
}

// ---------------- transpose Whh -> WhhT[d][k][r] ----------------
__global__ void k_whht(const float* __restrict__ Whh_f, const float* __restrict__ Whh_b,
                       float* __restrict__ WhhT){
  int d  = blockIdx.z;
  const float* Whh = d ? Whh_b : Whh_f;
  int rt = blockIdx.x*32, kt = blockIdx.y*32;
  int tx = threadIdx.x & 31, ty = threadIdx.x >> 5;
  __shared__ float tile[32][33];
  for (int i = ty; i < 32; i += 8)
    tile[i][tx] = Whh[(size_t)(rt+i)*HH + kt+tx];
  __syncthreads();
  for (int i = ty; i < 32; i += 8)
    WhhT[((size_t)d*HH + kt+i)*G4 + rt+tx] = tile[tx][i];
}

__global__ void k_zero(float* __restrict__ p, int n){
  int i = blockIdx.x*blockDim.x + threadIdx.x;
  if (i < n) p[i] = 0.f;
}

// ---------------- xg chunk GEMM: xg[tl][r][b] = Wih_d @ xn[tsrc] ------------
__global__ __launch_bounds__(256) void k_xg(const float* __restrict__ xnT,
        const float* __restrict__ Wih_f, const float* __restrict__ Wih_b,
        float* __restrict__ xg, int* __restrict__ cnt, int c){
  if (blockIdx.x == 0 && blockIdx.y == 0){
    if (threadIdx.x < 17)
      __hip_atomic_store(&cnt[threadIdx.x*16], 0, __ATOMIC_RELAXED, __HIP_MEMORY_SCOPE_AGENT);
    else if (threadIdx.x == 17)
      __hip_atomic_store(&cnt[384], 0, __ATOMIC_RELAXED, __HIP_MEMORY_SCOPE_AGENT);
  }
  int nb = blockIdx.x, rb = blockIdx.y;
  int d = rb >> 5, rloc0 = (rb & 31)*128;
  const float* Wih = d ? Wih_b : Wih_f;
  int tid = threadIdx.x;
  int tx = tid & 15, ty = tid >> 4;
  __shared__ float Al[16*132];
  __shared__ float Bl[16*132];
  float acc[8][8];
  #pragma unroll
  for (int i = 0; i < 8; i++)
    #pragma unroll
    for (int j = 0; j < 8; j++) acc[i][j] = 0.f;
  for (int kc = 0; kc < EE; kc += 16){
    #pragma unroll
    for (int j = 0; j < 8; j++){
      int idx = tid + j*256;
      int n = idx & 127, k = idx >> 7;
      int tglob = c*TCHUNK + nb*4 + (n >> 5);
      int tsrc = d ? (SS-1-tglob) : tglob;
      Al[k*132 + n] = xnT[((size_t)tsrc*EE + kc + k)*BB + (n & 31)];
    }
    #pragma unroll
    for (int j = 0; j < 8; j++){
      int idx = tid + j*256;
      int k = idx & 15, r = idx >> 4;
      Bl[k*132 + r] = Wih[(size_t)(rloc0 + r)*EE + kc + k];
    }
    __syncthreads();
    #pragma unroll
    for (int k = 0; k < 16; k++){
      float4 a0 = *(const float4*)(&Al[k*132 + tx*4]);
      float4 a1 = *(const float4*)(&Al[k*132 + 64 + tx*4]);
      float4 b0 = *(const float4*)(&Bl[k*132 + ty*4]);
      float4 b1 = *(const float4*)(&Bl[k*132 + 64 + ty*4]);
      float av[8] = {a0.x,a0.y,a0.z,a0.w,a1.x,a1.y,a1.z,a1.w};
      float bv[8] = {b0.x,b0.y,b0.z,b0.w,b1.x,b1.y,b1.z,b1.w};
      #pragma unroll
      for (int i = 0; i < 8; i++)
        #pragma unroll
        for (int j2 = 0; j2 < 8; j2++) acc[i][j2] += av[i]*bv[j2];
    }
    __syncthreads();
  }
  #pragma unroll
  for (int j = 0; j < 8; j++){
    int r = rloc0 + ((j < 4) ? (ty*4 + j) : (64 + ty*4 + j - 4));
    #pragma unroll
    for (int ig = 0; ig < 2; ig++){
      int n0 = ig*64 + tx*4;
      int tl = nb*4 + (n0 >> 5), b = n0 & 31;
      float4 o = make_float4(acc[ig*4+0][j], acc[ig*4+1][j], acc[ig*4+2][j], acc[ig*4+3][j]);
      *(float4*)(&xg[(((size_t)tl*8192) + d*G4 + r)*BB + b]) = o;
    }
  }
}

// ---------------- persistent-chunk LSTM: W in LDS, in-wave K-split ----------
// 256 blocks (1/CU) x 512 thr (8 waves). Per-direction barrier: d=0 blocks
// use lines 0-7 + flag cnt[256]; d=1 use lines 8-15 + flag cnt[384].
__global__ __launch_bounds__(512) void k_lstm(
    const float* __restrict__ WhhT,
    const float* __restrict__ bih_f, const float* __restrict__ bhh_f,
    const float* __restrict__ bih_b, const float* __restrict__ bhh_b,
    const float* __restrict__ xg, float* __restrict__ hbuf,
    float* __restrict__ cT, float* __restrict__ hs,
    int* __restrict__ cnt, int c)
{
  extern __shared__ float lsm[];
  float* Wl  = lsm;                 // [8][128*36 + 8]
  float* gl  = lsm + 36928;         // [32][36]
  float* cls = lsm + 38080;         // [8][32]

  const int blk = blockIdx.x;
  const int d   = blk >> 7;
  const int j0  = (blk & 127) * 8;
  const int tid = threadIdx.x;
  const int ln  = tid & 63;
  const int ksub = ln >> 3;          // 0..7 -> K slice of 128
  const int bg   = ln & 7;
  const int b0   = bg * 4;
  const int cbase = (tid >> 6) * 4;  // wave -> col quad

  const float* bih = d ? bih_b : bih_f;
  const float* bhh = d ? bhh_b : bhh_f;
  const float* WT_d = WhhT + (size_t)d * HH * G4;

  {
    const int cs = tid & 31;
    const int ks = tid >> 5;
    const int g  = cs >> 3, jj = cs & 7;
    const size_t rglob = (size_t)g*HH + j0 + jj;
    for (int kk = 0; kk < 64; kk++){
      int k = kk*16 + ks;
      Wl[(k >> 7)*WLKS + (k & 127)*36 + cs] = WT_d[(size_t)k*G4 + rglob];
    }
  }

  const int pjj = (tid >> 5) & 7, pb = tid & 31;
  float pbias[4];
  if (tid < 256){
    cls[pjj*32 + pb] = cT[((size_t)d*HH + j0 + pjj)*BB + pb];
    #pragma unroll
    for (int g2 = 0; g2 < 4; g2++)
      pbias[g2] = bih[g2*HH + j0 + pjj] + bhh[g2*HH + j0 + pjj];
  }
  __syncthreads();

  for (int tl = 0; tl < TCHUNK; tl++){
    const int s = c*TCHUNK + tl;
    const float* hprev = hbuf + ((size_t)((s & 1)*2 + d))*HH*BB;
    float*       hnext = hbuf + ((size_t)(((s+1) & 1)*2 + d))*HH*BB;

    float xgv[4] = {0.f,0.f,0.f,0.f};
    if (tid < 256){
      const size_t xbase = ((size_t)tl*8192 + (size_t)d*G4)*BB;
      #pragma unroll
      for (int g2 = 0; g2 < 4; g2++)
        xgv[g2] = xg[xbase + (size_t)(g2*HH + j0 + pjj)*BB + pb];
    }

    float acc[4][4];
    #pragma unroll
    for (int i = 0; i < 4; i++)
      #pragma unroll
      for (int j = 0; j < 4; j++) acc[i][j] = 0.f;

    {
      const float* hp = hprev + (size_t)(ksub*128)*BB + b0;
      const float* wrow = &Wl[ksub*WLKS + cbase];
      for (int ib = 0; ib < 128; ib += 16){
        float4 hv[16];
        #pragma unroll
        for (int u = 0; u < 16; u++)
          hv[u] = *(const float4*)(hp + (size_t)(ib+u)*BB);
        #pragma unroll
        for (int u = 0; u < 16; u++){
          float4 wv = *(const float4*)(wrow + (ib+u)*36);
          acc[0][0] += wv.x*hv[u].x; acc[0][1] += wv.x*hv[u].y; acc[0][2] += wv.x*hv[u].z; acc[0][3] += wv.x*hv[u].w;
          acc[1][0] += wv.y*hv[u].x; acc[1][1] += wv.y*hv[u].y; acc[1][2] += wv.y*hv[u].z; acc[1][3] += wv.y*hv[u].w;
          acc[2][0] += wv.z*hv[u].x; acc[2][1] += wv.z*hv[u].y; acc[2][2] += wv.z*hv[u].z; acc[2][3] += wv.z*hv[u].w;
          acc[3][0] += wv.w*hv[u].x; acc[3][1] += wv.w*hv[u].y; acc[3][2] += wv.w*hv[u].z; acc[3][3] += wv.w*hv[u].w;
        }
      }
    }
    #pragma unroll
    for (int i = 0; i < 4; i++)
      #pragma unroll
      for (int j = 0; j < 4; j++){
        float v = acc[i][j];
        v += __shfl_xor(v, 8, 64);
        v += __shfl_xor(v, 16, 64);
        v += __shfl_xor(v, 32, 64);
        acc[i][j] = v;
      }
    if (ksub == 0){
      #pragma unroll
      for (int i = 0; i < 4; i++){
        float4 o = make_float4(acc[i][0], acc[i][1], acc[i][2], acc[i][3]);
        *(float4*)(&gl[(cbase + i)*36 + b0]) = o;
      }
    }
    __syncthreads();
    if (tid < 256){
      float gv[4];
      #pragma unroll
      for (int g2 = 0; g2 < 4; g2++)
        gv[g2] = gl[(g2*8 + pjj)*36 + pb] + pbias[g2] + xgv[g2];
      float iv = sigm(gv[0]), fv = sigm(gv[1]), ggv = tanhf(gv[2]), ov = sigm(gv[3]);
      float cv = fv*cls[pjj*32 + pb] + iv*ggv;
      cls[pjj*32 + pb] = cv;
      float h = ov*tanhf(cv);
      hnext[(size_t)(j0 + pjj)*BB + pb] = h;
      int tsv = d ? (SS-1-s) : s;
      hs[(((size_t)d*SS + tsv)*HH + j0 + pjj)*BB + pb] = h;   // [d][t][j][b]
    }
    if (tl < TCHUNK-1){
      __syncthreads();
      if (tid == 0){
        __builtin_amdgcn_fence(__ATOMIC_RELEASE, "agent");
        __hip_atomic_fetch_add(&cnt[((blk & 7) + d*8)*16], 1, __ATOMIC_RELAXED, __HIP_MEMORY_SCOPE_AGENT);
        const int target = 16*(tl+1);
        const int flagidx = d ? 384 : 256;
        if ((blk & 127) == 0){
          const int lbase = d*8;
          int done = 0;
          while (done < 8){
            done = 0;
            #pragma unroll
            for (int i = 0; i < 8; i++)
              done += (__hip_atomic_load(&cnt[(lbase+i)*16], __ATOMIC_RELAXED, __HIP_MEMORY_SCOPE_AGENT) >= target);
            if (done < 8) __builtin_amdgcn_s_sleep(2);
          }
          __hip_atomic_store(&cnt[flagidx], tl+1, __ATOMIC_RELAXED, __HIP_MEMORY_SCOPE_AGENT);
        } else {
          while (__hip_atomic_load(&cnt[flagidx], __ATOMIC_RELAXED, __HIP_MEMORY_SCOPE_AGENT) < tl+1)
            __builtin_amdgcn_s_sleep(2);
        }
        __builtin_amdgcn_fence(__ATOMIC_ACQUIRE, "agent");
      }
      __syncthreads();
    }
  }
  __syncthreads();
  if (tid < 256)
    cT[((size_t)d*HH + j0 + pjj)*BB + pb] = cls[pjj*32 + pb];
}

// ---------------- LN(hs) + tanh(Wsq proj) -> xq[d][t][b][q] ----------------
// hs layout [d][t][j][b]
__global__ __launch_bounds__(256) void k_lnproj(const float* __restrict__ hs,
        const float* __restrict__ g_fw, const float* __restrict__ be_fw,
        const float* __restrict__ g_bk, const float* __restrict__ be_bk,
        const float* __restrict__ Wsq, const float* __restrict__ bsq,
        float* __restrict__ xq){
  int t = blockIdx.x, d = blockIdx.y;
  int tid = threadIdx.x;
  const float* gv  = d ? g_bk  : g_fw;
  const float* bev = d ? be_bk : be_fw;
  const float* hrow = hs + ((size_t)d*SS + t)*HH*BB;   // [HH][BB]
  __shared__ float red[256], red2[256];
  __shared__ float smu[32], srs[32];
  __shared__ float ln[32*132];
  __shared__ float wl[64*132];
  {
    int b = tid & 31, jg = tid >> 5;
    float s = 0.f, s2 = 0.f;
    for (int j = jg*128; j < jg*128+128; j++){
      float v = hrow[(size_t)j*BB + b];
      s += v; s2 += v*v;
    }
    red[b*8 + jg] = s; red2[b*8 + jg] = s2; __syncthreads();
    if (tid < 32){
      float a = 0.f, a2 = 0.f;
      for (int k = 0; k < 8; k++){ a += red[tid*8+k]; a2 += red2[tid*8+k]; }
      float mu = a*(1.f/HH), var = a2*(1.f/HH) - mu*mu;
      smu[tid] = mu; srs[tid] = rsqrtf(var + EPSF);
    }
    __syncthreads();
  }
  float acc[4][2] = {{0.f,0.f},{0.f,0.f},{0.f,0.f},{0.f,0.f}};
  int qg = tid & 31, bg = tid >> 5;
  int q0 = qg*2, b0g = bg*4;
  for (int jc = 0; jc < 8; jc++){
    for (int n = tid; n < 4096; n += 256){
      int b = n & 31, jj = n >> 5; int j = jc*128 + jj;
      float v = hrow[(size_t)j*BB + b];
      ln[b*132+jj] = (v - smu[b])*srs[b]*gv[j] + bev[j];
    }
    for (int n = tid; n < 8192; n += 256){
      int q = n >> 7, jj = n & 127;
      wl[q*132+jj] = Wsq[(size_t)q*HH + jc*128 + jj];
    }
    __syncthreads();
    for (int jj = 0; jj < 128; jj += 4){
      float4 w0 = *(const float4*)(&wl[q0*132+jj]);
      float4 w1 = *(const float4*)(&wl[(q0+1)*132+jj]);
      #pragma unroll
      for (int i = 0; i < 4; i++){
        float4 xv = *(const float4*)(&ln[(b0g+i)*132+jj]);
        acc[i][0] += xv.x*w0.x + xv.y*w0.y + xv.z*w0.z + xv.w*w0.w;
        acc[i][1] += xv.x*w1.x + xv.y*w1.y + xv.z*w1.z + xv.w*w1.w;
      }
    }
    __syncthreads();
  }
  #pragma unroll
  for (int i = 0; i < 4; i++)
    #pragma unroll
    for (int u = 0; u < 2; u++){
      float o = tanhf(acc[i][u] + bsq[q0+u]);
      xq[(((size_t)d*SS + t)*BB + (b0g+i))*QQ + q0 + u] = o;
    }
}

// ---------------- concat + LN + topic GEMM -> d_out topic_preds ----------------
__global__ __launch_bounds__(256) void k_topic(const float* __restrict__ xq,
        const float* __restrict__ g_sq, const float* __restrict__ be_sq,
        const float* __restrict__ Wtop, const float* __restrict__ btop,
        float* __restrict__ out){
  int t = blockIdx.x; int tid = threadIdx.x;
  __shared__ float xc[32*132];
  __shared__ float wl[16*520];
  __shared__ float red[256], red2[256];
  __shared__ float smu[32], srs[32];
  for (int n = tid; n < 4096; n += 256){
    int b = n >> 7, q = n & 127;
    float v = (q < 64) ? xq[(((size_t)0*SS + t)*BB + b)*QQ + q]
                       : xq[(((size_t)1*SS + t)*BB + b)*QQ + (q-64)];
    xc[b*132+q] = v;
  }
  __syncthreads();
  {
    int b = tid >> 3, sl = tid & 7;
    float s = 0.f, s2 = 0.f;
    for (int k = 0; k < 16; k++){ float v = xc[b*132 + sl*16 + k]; s += v; s2 += v*v; }
    red[tid] = s; red2[tid] = s2; __syncthreads();
    if (tid < 32){
      float a = 0.f, a2 = 0.f;
      for (int k = 0; k < 8; k++){ a += red[tid*8+k]; a2 += red2[tid*8+k]; }
      float mu = a*(1.f/128.f), var = a2*(1.f/128.f) - mu*mu;
      smu[tid] = mu; srs[tid] = rsqrtf(var + EPSF);
    }
    __syncthreads();
    for (int n = tid; n < 4096; n += 256){
      int b2 = n >> 7, q = n & 127;
      xc[b2*132+q] = (xc[b2*132+q]-smu[b2])*srs[b2]*g_sq[q] + be_sq[q];
    }
    __syncthreads();
  }
  int og = tid & 63, bg = tid >> 6;
  int o0 = og*8, b0 = bg*8;
  float acc[8][8];
  #pragma unroll
  for (int i = 0; i < 8; i++)
    #pragma unroll
    for (int j = 0; j < 8; j++) acc[i][j] = 0.f;
  for (int kc = 0; kc < 128; kc += 16){
    for (int n = tid; n < 8192; n += 256){
      int o = n >> 4, kk = n & 15;
      wl[kk*520 + o] = Wtop[(size_t)o*128 + kc + kk];
    }
    __syncthreads();
    #pragma unroll
    for (int kk = 0; kk < 16; kk++){
      float4 w0 = *(const float4*)(&wl[kk*520+o0]);
      float4 w1 = *(const float4*)(&wl[kk*520+o0+4]);
      float wv[8] = {w0.x,w0.y,w0.z,w0.w,w1.x,w1.y,w1.z,w1.w};
      int k = kc + kk;
      #pragma unroll
      for (int bi = 0; bi < 8; bi++){
        float xv = xc[(b0+bi)*132 + k];
        #pragma unroll
        for (int oi = 0; oi < 8; oi++) acc[bi][oi] += xv*wv[oi];
      }
    }
    __syncthreads();
  }
  #pragma unroll
  for (int bi = 0; bi < 8; bi++){
    int b = b0 + bi;
    #pragma unroll
    for (int oi = 0; oi < 8; oi++)
      out[((size_t)t*BB + b)*TTOP + o0 + oi] = acc[bi][oi] + btop[o0+oi];
  }
}

// ---------------- per-(dir,batch): mean, center, covariance ----------------
__global__ __launch_bounds__(256) void k_pca1(const float* __restrict__ xq,
        float* __restrict__ cmat, float* __restrict__ covg){
  int u = blockIdx.x; int d = u >> 5, b = u & 31;
  int tid = threadIdx.x;
  __shared__ float red[256];
  __shared__ float smq[64];
  {
    int q = tid & 63, tg = tid >> 6;
    float s = 0.f;
    for (int t2 = tg*64; t2 < tg*64+64; t2++)
      s += xq[(((size_t)d*SS + t2)*BB + b)*QQ + q];
    red[tid] = s; __syncthreads();
    if (tid < 64) smq[tid] = (red[tid]+red[tid+64]+red[tid+128]+red[tid+192])*(1.f/SS);
    __syncthreads();
  }
  float* cm = cmat + (size_t)u*SS*QQ;
  for (int n = tid; n < SS*QQ; n += 256){
    int t2 = n >> 6, q = n & 63;
    cm[n] = xq[(((size_t)d*SS + t2)*BB + b)*QQ + q] - smq[q];
  }
  __syncthreads();
  {
    int pg = (tid & 15)*4, qg = (tid >> 4)*4;
    float a[4][4] = {{0}};
    for (int t2 = 0; t2 < SS; t2++){
      const float* cr = cm + (size_t)t2*QQ;
      float4 cp = *(const float4*)(cr+pg);
      float4 cq = *(const float4*)(cr+qg);
      float pv[4] = {cp.x,cp.y,cp.z,cp.w}, qv[4] = {cq.x,cq.y,cq.z,cq.w};
      #pragma unroll
      for (int i = 0; i < 4; i++)
        #pragma unroll
        for (int j2 = 0; j2 < 4; j2++) a[i][j2] += pv[i]*qv[j2];
    }
    #pragma unroll
    for (int i = 0; i < 4; i++)
      #pragma unroll
      for (int j2 = 0; j2 < 4; j2++)
        covg[(size_t)u*4096 + (pg+i)*64 + qg+j2] = a[i][j2]*(1.f/SS);
  }
}

// ---------------- project + smooth + adjacent-cos ----------------
__global__ __launch_bounds__(256) void k_pca2(const float* __restrict__ cmat,
        const float* __restrict__ Pg, const float* __restrict__ kern,
        float* __restrict__ cosb){
  int u = blockIdx.x; int tid = threadIdx.x;
  __shared__ float sP[1024];
  __shared__ float sE[4096];
  __shared__ float sY[4096];
  __shared__ float kb[121];
  __shared__ float nn2[256];
  if (tid < 121) kb[tid] = kern[tid];
  for (int n = tid; n < 1024; n += 256) sP[n] = Pg[(size_t)u*1024 + n];
  __syncthreads();
  const float* cm = cmat + (size_t)u*SS*QQ;
  for (int m = tid; m < SS*NPC; m += 256){
    int t2 = m >> 4, n = m & 15;
    const float* cr = cm + (size_t)t2*QQ;
    float acc = 0.f;
    for (int i = 0; i < 64; i++) acc += cr[i]*sP[i*16+n];
    sE[m] = acc;
  }
  __syncthreads();
  for (int m = tid; m < SS*NPC; m += 256){
    int t2 = m >> 4, n = m & 15;
    float acc = 0.f;
    for (int a2 = 0; a2 < 11; a2++){
      int ta = t2 + a2 - 5;
      if (ta < 0 || ta >= SS) continue;
      #pragma unroll
      for (int b2 = 0; b2 < 11; b2++){
        int nb = n + b2 - 5;
        if (nb < 0 || nb >= NPC) continue;
        acc += kb[a2*11+b2]*sE[ta*16+nb];
      }
    }
    sY[m] = acc;
  }
  __syncthreads();
  {
    float acc = 0.f;
    #pragma unroll
    for (int n = 0; n < 16; n++){ float v = sY[tid*16+n]; acc += v*v; }
    nn2[tid] = acc;
  }
  __syncthreads();
  if (tid < 255){
    float num = 0.f;
    #pragma unroll
    for (int n = 0; n < 16; n++) num += sY[tid*16+n]*sY[(tid+1)*16+n];
    cosb[(size_t)u*256 + tid] = num/(sqrtf(nn2[tid])*sqrtf(nn2[tid+1]));
  }
}

// ---------------- d = sqrt(cf*cb); pos = argmax ----------------
__global__ void k_pos(const float* __restrict__ cosb, float* __restrict__ out){
  __shared__ float mx[256];
  __shared__ int   mi[256];
  int tid = threadIdx.x;
  for (int b = 0; b < 32; b++){
    float v = -1e30f;
    if (tid < 255){
      float cf = cosb[(size_t)(b)*256 + tid];
      float cb = cosb[(size_t)(32+b)*256 + tid];
      v = sqrtf(cf*cb);
      if (isnan(v)) v = INFINITY;
    }
    mx[tid] = v; __syncthreads();
    for (int st = 128; st > 0; st >>= 1){
      if (tid < st) mx[tid] = fmaxf(mx[tid], mx[tid+st]);
      __syncthreads();
    }
    float m = mx[0]; __syncthreads();
    mi[tid] = (tid < 255 && v == m) ? tid : (1<<30);
    __syncthreads();
    for (int st = 128; st > 0; st >>= 1){
      if (tid < st) mi[tid] = min(mi[tid], mi[tid+st]);
      __syncthreads();
    }
    if (tid == 0) out[(size_t)SS*BB*TTOP + b] = (float)mi[0];
    __syncthreads();
  }
}

// ---------------- launch ----------------
extern "C" void kernel_launch(void* const* d_in, const int* in_sizes, int n_in,
                              void* d_out, int out_size, void* d_ws, size_t ws_size,
                              hipStream_t stream){
  (void)in_sizes; (void)n_in; (void)out_size; (void)ws_size;
  const float* x      = (const float*)d_in[0];
  const float* Wih_f  = (const float*)d_in[1];
  const float* Whh_f  = (const float*)d_in[2];
  const float* bih_f  = (const float*)d_in[3];
  const float* bhh_f  = (const float*)d_in[4];
  const float* Wih_b  = (const float*)d_in[5];
  const float* Whh_b  = (const float*)d_in[6];
  const float* bih_b  = (const float*)d_in[7];
  const float* bhh_b  = (const float*)d_in[8];
  const float* g_in   = (const float*)d_in[9];
  const float* be_in  = (const float*)d_in[10];
  const float* g_fw   = (const float*)d_in[11];
  const float* be_fw  = (const float*)d_in[12];
  const float* g_bk   = (const float*)d_in[13];
  const float* be_bk  = (const float*)d_in[14];
  const float* g_sq   = (const float*)d_in[15];
  const float* be_sq  = (const float*)d_in[16];
  const float* Wsq    = (const float*)d_in[17];
  const float* bsq    = (const float*)d_in[18];
  const float* Wtop   = (const float*)d_in[19];
  const float* btop   = (const float*)d_in[20];
  const float* gkern  = (const float*)d_in[21];

  float* ws    = (float*)d_ws;
  float* xnT   = ws + OFF_XNT;
  float* WhhT  = ws + OFF_WHHT;
  float* cT    = ws + OFF_CT;
  float* hbuf  = ws + OFF_HBUF;
  int*   cnt   = (int*)(ws + OFF_CNT);
  float* xg    = ws + OFF_XG;
  float* hs    = ws + OFF_HS;
  float* xq    = ws + OFF_XQ;
  float* cmat  = ws + OFF_CMAT;
  float* covg  = ws + OFF_COV;
  float* Pg    = ws + OFF_PG;
  float* cosb  = ws + OFF_COS;
  float* out   = (float*)d_out;

  hipFuncSetAttribute((const void*)k_eig,
                      hipFuncAttributeMaxDynamicSharedMemorySize, EIG_DYN_LDS);
  hipFuncSetAttribute((const void*)k_lstm,
                      hipFuncAttributeMaxDynamicSharedMemorySize, LSTM_DYN_LDS);

  k_zero<<<dim3(768), dim3(256), 0, stream>>>(cT, 196608);   // cT + hbuf
  k_ln_in<<<dim3(SS*BB), dim3(256), 0, stream>>>(x, g_in, be_in, xnT);
  k_whht<<<dim3(128, 32, 2), dim3(256), 0, stream>>>(Whh_f, Whh_b, WhhT);
  for (int c = 0; c < SS/TCHUNK; c++){
    k_xg<<<dim3(8, 64), dim3(256), 0, stream>>>(xnT, Wih_f, Wih_b, xg, cnt, c);
    k_lstm<<<dim3(NBLK), dim3(512), LSTM_DYN_LDS, stream>>>(WhhT, bih_f, bhh_f, bih_b, bhh_b,
                                                            xg, hbuf, cT, hs, cnt, c);
  }
  k_lnproj<<<dim3(SS,2), dim3(256), 0, stream>>>(hs, g_fw, be_fw, g_bk, be_bk, Wsq, bsq, xq);
  k_topic<<<dim3(SS), dim3(256), 0, stream>>>(xq, g_sq, be_sq, Wtop, btop, out);
  k_pca1<<<dim3(64), dim3(256), 0, stream>>>(xq, cmat, covg);
  k_eig<<<dim3(64), dim3(256), EIG_DYN_LDS, stream>>>(covg, Pg);
  k_pca2<<<dim3(64), dim3(256), 0, stream>>>(cmat, Pg, gkern, cosb);
  k_pos<<<dim3(1), dim3(256), 0, stream>>>(cosb, out);
}